// Round 10
// baseline (262.943 us; speedup 1.0000x reference)
//
#include <hip/hip_runtime.h>
#include <math.h>

typedef float2 c32;

__device__ __forceinline__ c32 cmulc(c32 a, c32 b){
    return make_float2(fmaf(a.x, b.x, -(a.y*b.y)), fmaf(a.x, b.y, a.y*b.x));
}
__device__ __forceinline__ c32 caddc(c32 a, c32 b){ return make_float2(a.x+b.x, a.y+b.y); }
__device__ __forceinline__ c32 csubc(c32 a, c32 b){ return make_float2(a.x-b.x, a.y-b.y); }

// In-register DIT FFT of size N (8 or 16), natural-order in/out.
// tw[m] = e^{sign*2*pi*i*m/16}  (sign baked into the table the caller built).
template<int N>
__device__ __forceinline__ void fftN(c32* a, const c32* tw){
    constexpr int LOG = (N == 16) ? 4 : 3;
    c32 b[N];
    #pragma unroll
    for (int i = 0; i < N; ++i){
        int r = 0;
        #pragma unroll
        for (int bb = 0; bb < LOG; ++bb) r = (r << 1) | ((i >> bb) & 1);
        b[i] = a[r];
    }
    #pragma unroll
    for (int len = 2; len <= N; len <<= 1){
        #pragma unroll
        for (int i = 0; i < N; i += len){
            #pragma unroll
            for (int j = 0; j < len/2; ++j){
                c32 t = b[i + j + len/2];
                if (j) t = cmulc(tw[j * (16/len)], t);
                c32 u = b[i + j];
                b[i + j]         = caddc(u, t);
                b[i + j + len/2] = csubc(u, t);
            }
        }
    }
    #pragma unroll
    for (int i = 0; i < N; ++i) a[i] = b[i];
}

// ---------------------------------------------------------------------------
// 1) conv3x3 stride2 SAME + gelu + partial spatial sums (deterministic)
//    grid = 128 frames x 32 stripes (2 output rows), 512 thr.
//    Thread = 1 position x 8 channels; weights = 54 VGPRs loaded ONCE
//    (no scalar-load stream in the FMA loop).  Taps from a 7.8 KB LDS slab.
//    Reduce: 4-lane-stride shuffles (16 positions) -> 1 KB LDS transpose.
//    part[(bt*32+sr)*32 + c] = stripe partial sum of gelu(conv)
// ---------------------------------------------------------------------------
__global__ __launch_bounds__(512) void k_conv(const float* __restrict__ in,
                                              const float* __restrict__ cw,
                                              const float* __restrict__ cb,
                                              float* __restrict__ part)
{
    __shared__ float xs[5 * 392];          // input rows r0..r0+4, cols 0..391
    __shared__ float red[8 * 33];          // [wave][cg*8+ch]
    const int tid = threadIdx.x;           // 0..511
    const int bt  = blockIdx.x >> 5;
    const int sr  = blockIdx.x & 31;
    const int r0  = 4 * sr;                // first input row of the stripe

    const int cg  = tid & 3;               // channel group: ch 8cg..8cg+7
    const int pos = tid >> 2;              // 0..127 output position

    // weights in VGPRs (loaded once; 4 lanes share each address -> coalesced)
    float4 wa[27], wb[27];
    #pragma unroll
    for (int q = 0; q < 27; ++q){
        wa[q] = *(const float4*)&cw[q * 32 + cg * 8];
        wb[q] = *(const float4*)&cw[q * 32 + cg * 8 + 4];
    }
    const float4 ba = *(const float4*)&cb[cg * 8];
    const float4 bb = *(const float4*)&cb[cg * 8 + 4];

    // stage slab as float4 (cols 384..391 zero, rows past bottom zero)
    const float4* src4 = (const float4*)(in + (size_t)bt * 49152 + (size_t)r0 * 384);
    const float4 z4 = make_float4(0.f, 0.f, 0.f, 0.f);
    for (int i = tid; i < 5 * 98; i += 512){
        int r = i / 98, c4 = i - r * 98;
        float4 v = z4;
        if (c4 < 96 && (r0 + r) < 128) v = src4[r * 96 + c4];
        *(float4*)&xs[r * 392 + c4 * 4] = v;
    }
    __syncthreads();

    const int oyl = pos >> 6;              // local output row 0..1
    const int ox  = pos & 63;              // output col

    // taps: 3 rows x 9 contiguous floats at float-col 6*ox (4-lane broadcast)
    float f[27];
    #pragma unroll
    for (int ky = 0; ky < 3; ++ky){
        const int rb = (2 * oyl + ky) * 392 + 6 * ox;
        #pragma unroll
        for (int j = 0; j < 9; ++j) f[ky * 9 + j] = xs[rb + j];
    }

    float s[8];
    s[0]=ba.x; s[1]=ba.y; s[2]=ba.z; s[3]=ba.w;
    s[4]=bb.x; s[5]=bb.y; s[6]=bb.z; s[7]=bb.w;
    #pragma unroll
    for (int q = 0; q < 27; ++q){
        const float fv = f[q];
        s[0] = fmaf(fv, wa[q].x, s[0]);
        s[1] = fmaf(fv, wa[q].y, s[1]);
        s[2] = fmaf(fv, wa[q].z, s[2]);
        s[3] = fmaf(fv, wa[q].w, s[3]);
        s[4] = fmaf(fv, wb[q].x, s[4]);
        s[5] = fmaf(fv, wb[q].y, s[5]);
        s[6] = fmaf(fv, wb[q].z, s[6]);
        s[7] = fmaf(fv, wb[q].w, s[7]);
    }

    // gelu (fast tanh via exp2/rcp) + in-wave reduce over 16 position-slots
    #pragma unroll
    for (int ch = 0; ch < 8; ++ch){
        const float v  = s[ch];
        const float u_ = 0.7978845608028654f * fmaf(0.044715f * v, v * v, v);
        const float e_ = __builtin_amdgcn_exp2f(2.8853900817779268f * u_);
        const float t_ = 1.0f - 2.0f * __builtin_amdgcn_rcpf(1.0f + e_);
        float r = 0.5f * v * (1.0f + t_);
        r += __shfl_down(r, 4, 64);
        r += __shfl_down(r, 8, 64);
        r += __shfl_down(r, 16, 64);
        r += __shfl_down(r, 32, 64);
        s[ch] = r;
    }
    const int wave = tid >> 6, lane = tid & 63;
    if (lane < 4){
        #pragma unroll
        for (int ch = 0; ch < 8; ++ch)
            red[wave * 33 + lane * 8 + ch] = s[ch];
    }
    __syncthreads();
    if (tid < 32){
        float acc = 0.0f;
        #pragma unroll
        for (int w = 0; w < 8; ++w) acc += red[w * 33 + tid];
        part[(size_t)blockIdx.x * 32 + tid] = acc;
    }
}

// ---------------------------------------------------------------------------
// 2) merged small kernel: blocks 0..1 = gates (384 threads of work),
//    blocks 2..196 = spectral rfft2 of padded k_exc/k_inh (direct 256-tap DFT)
// ---------------------------------------------------------------------------
__global__ __launch_bounds__(256) void k_small(const float* __restrict__ part,
    const float* __restrict__ wA, const float* __restrict__ bA,
    const float* __restrict__ wD, const float* __restrict__ bD,
    const float* __restrict__ wM, const float* __restrict__ bM,
    const float* __restrict__ wG, const float* __restrict__ bG,
    float* __restrict__ gA, float* __restrict__ gD,
    float* __restrict__ gM, float* __restrict__ gG,
    const float* __restrict__ k_exc, const float* __restrict__ k_inh,
    float* __restrict__ KEw, float* __restrict__ KIw)
{
    const int tid = threadIdx.x;
    if (blockIdx.x < 2){
        int g = blockIdx.x * 256 + tid;
        if (g >= 384) return;
        int bt = g / 3, c = g % 3;
        float sA = bA[c], sD = bD[c], sM = bM[c], sG = bG[c];
        for (int j = 0; j < 32; ++j){
            float cs = 0.f;
            #pragma unroll
            for (int q = 0; q < 32; ++q) cs += part[(bt*32 + q)*32 + j];
            cs *= (1.0f / 4096.0f);
            sA = fmaf(cs, wA[j*3+c], sA);
            sD = fmaf(cs, wD[j*3+c], sD);
            sM = fmaf(cs, wM[j*3+c], sM);
            sG = fmaf(cs, wG[j*3+c], sG);
        }
        gA[g] = 1.0f / (1.0f + expf(-sA));
        gD[g] = 1.0f / (1.0f + expf(-sD));
        gM[g] = fmaxf(sM, 0.f) + log1pf(expf(-fabsf(sM)));
        gG[g] = fmaxf(sG, 0.f) + log1pf(expf(-fabsf(sG)));
        return;
    }
    __shared__ c32 Wt[128];
    if (tid < 128){
        float ang = -0.049087385212340517f * (float)tid;   // -2*pi*t/128
        float s, co; sincosf(ang, &s, &co);
        Wt[tid] = make_float2(co, s);
    }
    __syncthreads();
    int g = (blockIdx.x - 2) * 256 + tid;
    if (g >= 2 * 24960) return;
    int which = g / 24960, r = g % 24960;
    int c = r / 8320, uv = r % 8320;
    int u_ = uv / 65, v_ = uv % 65;
    const float* kk = which ? k_inh : k_exc;
    float ar = 0.f, ai = 0.f;
    for (int y = 0; y < 16; ++y){
        int pu = u_ * (56 + y);
        #pragma unroll
        for (int x = 0; x < 16; ++x){
            int idx = (pu + v_ * (56 + x)) & 127;
            float kv = kk[(y*16 + x)*3 + c];
            c32 w = Wt[idx];
            ar = fmaf(kv, w.x, ar);
            ai = fmaf(kv, w.y, ai);
        }
    }
    ((float2*)(which ? KIw : KEw))[c*8320 + uv] = make_float2(ar, ai);
}

// ---------------------------------------------------------------------------
// 4) forward rfft2 per (b,t,c) image.  Single 65KB LDS buffer (2 blocks/CU).
//    FFT-128 = radix-16 (in-place, task-owned slots) then radix-8
//    (read-all -> barrier -> write-all).  Hermitian unpack same-buffer.
// ---------------------------------------------------------------------------
__global__ __launch_bounds__(512, 4) void k_fft_fwd(const float* __restrict__ in,
                                                    float* __restrict__ U_ws)
{
    __shared__ c32 S[8320];                 // rows: [64][130]; cols: [128][65]
    __shared__ c32 Wt[128];                 // e^{-2 pi i t/128}
    const int tid = threadIdx.x;
    const int img = blockIdx.x;             // bt*3 + c
    const int bt = img / 3, c = img % 3;

    if (tid < 128){
        float ang = -0.049087385212340517f * (float)tid;
        float s, co; sincosf(ang, &s, &co);
        Wt[tid] = make_float2(co, s);
    }
    __syncthreads();
    c32 twb[8];
    #pragma unroll
    for (int m = 0; m < 8; ++m) twb[m] = Wt[8*m];   // 16th roots (serves FFT8 too)

    // pack: S[r*130+x] = in[2r][x] + i*in[2r+1][x]
    const float* src = in + (size_t)bt * 49152 + c;
    for (int p = tid; p < 8192; p += 512){
        int r = p >> 7, x = p & 127;
        float re = src[(size_t)((2*r)   * 128 + x) * 3];
        float im = src[(size_t)((2*r+1) * 128 + x) * 3];
        S[r*130 + x] = make_float2(re, im);
    }
    __syncthreads();

    // row stage1: FFT16 over n2 at slots n1+8*n2 (task-owned, in place),
    // then twiddle W128^{n1*k2}.  512 tasks = 512 threads.
    {
        int r = tid >> 3, n1 = tid & 7;
        c32 v[16];
        #pragma unroll
        for (int n2 = 0; n2 < 16; ++n2) v[n2] = S[r*130 + n1 + 8*n2];
        fftN<16>(v, twb);
        #pragma unroll
        for (int k2 = 0; k2 < 16; ++k2)
            S[r*130 + n1 + 8*k2] = (n1 && k2) ? cmulc(Wt[n1*k2], v[k2]) : v[k2];
    }
    __syncthreads();
    // row stage2: FFT8 over n1 (slots 8k2..8k2+7) -> slots k2+16*k1.
    // 1024 tasks, read-all/sync/write-all.
    {
        c32 g0[8], g1[8];
        const int t1 = tid + 512;
        {
            int r = tid >> 4, k2 = tid & 15;
            #pragma unroll
            for (int n1 = 0; n1 < 8; ++n1) g0[n1] = S[r*130 + 8*k2 + n1];
            fftN<8>(g0, twb);
        }
        {
            int r = t1 >> 4, k2 = t1 & 15;
            #pragma unroll
            for (int n1 = 0; n1 < 8; ++n1) g1[n1] = S[r*130 + 8*k2 + n1];
            fftN<8>(g1, twb);
        }
        __syncthreads();
        {
            int r = tid >> 4, k2 = tid & 15;
            #pragma unroll
            for (int k1 = 0; k1 < 8; ++k1) S[r*130 + k2 + 16*k1] = g0[k1];
        }
        {
            int r = t1 >> 4, k2 = t1 & 15;
            #pragma unroll
            for (int k1 = 0; k1 < 8; ++k1) S[r*130 + k2 + 16*k1] = g1[k1];
        }
    }
    __syncthreads();
    // unpack packed real rows -> C[128][65] layout, same buffer.
    // 4160 tasks; read-all/sync/write-all (<=9 tasks/thread).
    {
        c32 e0[9], e1[9];
        #pragma unroll
        for (int j = 0; j < 9; ++j){
            int task = tid + 512*j;
            if (task < 4160){
                int r = task / 65, v_ = task % 65;
                c32 zk = S[r*130 + v_];
                c32 zn = S[r*130 + ((128 - v_) & 127)];
                e0[j] = make_float2(0.5f*(zk.x + zn.x),  0.5f*(zk.y - zn.y));
                e1[j] = make_float2(0.5f*(zk.y + zn.y), -0.5f*(zk.x - zn.x));
            }
        }
        __syncthreads();
        #pragma unroll
        for (int j = 0; j < 9; ++j){
            int task = tid + 512*j;
            if (task < 4160){
                int r = task / 65, v_ = task % 65;
                S[(2*r)  *65 + v_] = e0[j];
                S[(2*r+1)*65 + v_] = e1[j];
            }
        }
    }
    __syncthreads();
    // col stage1: FFT16 over n2 at rows n1+8*n2 (task-owned), twiddle. 520 tasks.
    for (int task = tid; task < 520; task += 512){
        int n1 = task / 65, v_ = task % 65;
        c32 v[16];
        #pragma unroll
        for (int n2 = 0; n2 < 16; ++n2) v[n2] = S[(n1 + 8*n2)*65 + v_];
        fftN<16>(v, twb);
        #pragma unroll
        for (int k2 = 0; k2 < 16; ++k2)
            S[(n1 + 8*k2)*65 + v_] = (n1 && k2) ? cmulc(Wt[n1*k2], v[k2]) : v[k2];
    }
    __syncthreads();
    // col stage2: FFT8 over n1 (rows 8k2..8k2+7) -> rows k2+16*k1. 1040 tasks.
    {
        c32 g0[8], g1[8], g2[8];
        const int t1 = tid + 512, t2 = tid + 1024;
        {
            int k2 = tid / 65, v_ = tid % 65;
            #pragma unroll
            for (int n1 = 0; n1 < 8; ++n1) g0[n1] = S[(8*k2 + n1)*65 + v_];
            fftN<8>(g0, twb);
        }
        {
            int k2 = t1 / 65, v_ = t1 % 65;
            #pragma unroll
            for (int n1 = 0; n1 < 8; ++n1) g1[n1] = S[(8*k2 + n1)*65 + v_];
            fftN<8>(g1, twb);
        }
        if (t2 < 1040){
            int k2 = t2 / 65, v_ = t2 % 65;
            #pragma unroll
            for (int n1 = 0; n1 < 8; ++n1) g2[n1] = S[(8*k2 + n1)*65 + v_];
            fftN<8>(g2, twb);
        }
        __syncthreads();
        {
            int k2 = tid / 65, v_ = tid % 65;
            #pragma unroll
            for (int k1 = 0; k1 < 8; ++k1) S[(k2 + 16*k1)*65 + v_] = g0[k1];
        }
        {
            int k2 = t1 / 65, v_ = t1 % 65;
            #pragma unroll
            for (int k1 = 0; k1 < 8; ++k1) S[(k2 + 16*k1)*65 + v_] = g1[k1];
        }
        if (t2 < 1040){
            int k2 = t2 / 65, v_ = t2 % 65;
            #pragma unroll
            for (int k1 = 0; k1 < 8; ++k1) S[(k2 + 16*k1)*65 + v_] = g2[k1];
        }
    }
    __syncthreads();
    float2* dst = ((float2*)U_ws) + (size_t)img * 8320;
    for (int p = tid; p < 8320; p += 512) dst[p] = S[p];
}

// ---------------------------------------------------------------------------
// 5) sequential T-scan, U -> Y (separate buffers; compiler hoists U loads).
//    x' = 0.9a*x + (-KI*mu)*y + U ; y' = (KE*ga)*x + 0.9d*y.
// ---------------------------------------------------------------------------
__global__ __launch_bounds__(256) void k_scan(const float* __restrict__ U,
    float* __restrict__ Y,
    const float* __restrict__ KEw, const float* __restrict__ KIw,
    const float* __restrict__ gA, const float* __restrict__ gD,
    const float* __restrict__ gM, const float* __restrict__ gG)
{
    int g = blockIdx.x * 256 + threadIdx.x;
    if (g >= 4*3*128*65) return;
    int b = g / 24960, r = g % 24960;
    int c = r / 8320, uv = r % 8320;
    float2 ke = ((const float2*)KEw)[c*8320 + uv];
    float2 ki = ((const float2*)KIw)[c*8320 + uv];
    const float2* Up = (const float2*)U;
    float2* Yp = (float2*)Y;
    float xr = 0.f, xi = 0.f, yr = 0.f, yi = 0.f;
    #pragma unroll
    for (int t = 0; t < 32; ++t){
        int btc = (b*32 + t)*3 + c;
        float al = 0.9f * gA[btc], de = 0.9f * gD[btc];
        float mu = gM[btc],       ga = gG[btc];
        float axr = -ki.x * mu, axi = -ki.y * mu;
        float ayr =  ke.x * ga, ayi =  ke.y * ga;
        size_t iu = (size_t)btc * 8320 + uv;
        float2 uin = Up[iu];
        float nxr = fmaf(al, xr, fmaf(axr, yr, fmaf(-axi, yi, uin.x)));
        float nxi = fmaf(al, xi, fmaf(axr, yi, fmaf( axi, yr, uin.y)));
        float nyr = fmaf(ayr, xr, fmaf(-ayi, xi, de * yr));
        float nyi = fmaf(ayr, xi, fmaf( ayi, xr, de * yi));
        Yp[iu] = make_float2(nyr, nyi);
        xr = nxr; xi = nxi; yr = nyr; yi = nyi;
    }
}

// ---------------------------------------------------------------------------
// 6) inverse rfft2, single 65KB LDS buffer (2 blocks/CU).
//    col IFFT-128 (radix-16 in-place + radix-8 r/s/w), Hermitian EO-prep
//    paired-task in-place, row IFFT-64 (radix-8 in-place + radix-8 r/s/w).
// ---------------------------------------------------------------------------
__global__ __launch_bounds__(512, 4) void k_fft_inv(const float* __restrict__ Y_ws,
                                                    float* __restrict__ out)
{
    __shared__ c32 S[8320];                 // [128][65]
    __shared__ c32 Wt[128];                 // e^{+2 pi i t/128}
    const int tid = threadIdx.x;
    const int img = blockIdx.x;
    const int bt = img / 3, c = img % 3;

    if (tid < 128){
        float ang = 0.049087385212340517f * (float)tid;
        float s, co; sincosf(ang, &s, &co);
        Wt[tid] = make_float2(co, s);
    }
    __syncthreads();
    c32 twb[8];
    #pragma unroll
    for (int m = 0; m < 8; ++m) twb[m] = Wt[8*m];

    const float2* srcv = ((const float2*)Y_ws) + (size_t)img * 8320;
    for (int p = tid; p < 8320; p += 512) S[p] = srcv[p];
    __syncthreads();

    // col IFFT stage1: FFT16 over n2 at rows n1+8*n2 (task-owned). 520 tasks.
    for (int task = tid; task < 520; task += 512){
        int n1 = task / 65, v_ = task % 65;
        c32 v[16];
        #pragma unroll
        for (int n2 = 0; n2 < 16; ++n2) v[n2] = S[(n1 + 8*n2)*65 + v_];
        fftN<16>(v, twb);
        #pragma unroll
        for (int k2 = 0; k2 < 16; ++k2)
            S[(n1 + 8*k2)*65 + v_] = (n1 && k2) ? cmulc(Wt[n1*k2], v[k2]) : v[k2];
    }
    __syncthreads();
    // col IFFT stage2: FFT8 over n1 -> rows k2+16*k1. 1040 tasks, r/s/w.
    {
        c32 g0[8], g1[8], g2[8];
        const int t1 = tid + 512, t2 = tid + 1024;
        {
            int k2 = tid / 65, v_ = tid % 65;
            #pragma unroll
            for (int n1 = 0; n1 < 8; ++n1) g0[n1] = S[(8*k2 + n1)*65 + v_];
            fftN<8>(g0, twb);
        }
        {
            int k2 = t1 / 65, v_ = t1 % 65;
            #pragma unroll
            for (int n1 = 0; n1 < 8; ++n1) g1[n1] = S[(8*k2 + n1)*65 + v_];
            fftN<8>(g1, twb);
        }
        if (t2 < 1040){
            int k2 = t2 / 65, v_ = t2 % 65;
            #pragma unroll
            for (int n1 = 0; n1 < 8; ++n1) g2[n1] = S[(8*k2 + n1)*65 + v_];
            fftN<8>(g2, twb);
        }
        __syncthreads();
        {
            int k2 = tid / 65, v_ = tid % 65;
            #pragma unroll
            for (int k1 = 0; k1 < 8; ++k1) S[(k2 + 16*k1)*65 + v_] = g0[k1];
        }
        {
            int k2 = t1 / 65, v_ = t1 % 65;
            #pragma unroll
            for (int k1 = 0; k1 < 8; ++k1) S[(k2 + 16*k1)*65 + v_] = g1[k1];
        }
        if (t2 < 1040){
            int k2 = t2 / 65, v_ = t2 % 65;
            #pragma unroll
            for (int k1 = 0; k1 < 8; ++k1) S[(k2 + 16*k1)*65 + v_] = g2[k1];
        }
    }
    __syncthreads();
    // EO prep: paired tasks (k, 64-k) per row -> in-place. 128*33 tasks.
    // Z[k] = E[k] + i*O[k]; numpy drops imag of bins 0,64.
    for (int task = tid; task < 128*33; task += 512){
        int y = task / 33, k = task % 33;
        c32 Xk = S[y*65 + k];
        c32 Xn = S[y*65 + 64 - k];
        if (k == 0){ Xk.y = 0.f; Xn.y = 0.f; }
        float Er = 0.5f*(Xk.x + Xn.x), Ei = 0.5f*(Xk.y - Xn.y);
        c32 d  = make_float2(0.5f*(Xk.x - Xn.x), 0.5f*(Xk.y + Xn.y));
        c32 O  = cmulc(Wt[k], d);
        S[y*65 + k] = make_float2(Er - O.y, Ei + O.x);
        if (k > 0 && k < 32){
            float Er2 = 0.5f*(Xn.x + Xk.x), Ei2 = 0.5f*(Xn.y - Xk.y);
            c32 d2 = make_float2(0.5f*(Xn.x - Xk.x), 0.5f*(Xn.y + Xk.y));
            c32 O2 = cmulc(Wt[64 - k], d2);
            S[y*65 + 64 - k] = make_float2(Er2 - O2.y, Ei2 + O2.x);
        }
    }
    __syncthreads();
    // row IFFT-64 stage1: FFT8 over n2 at slots n1+8*n2 (task-owned),
    // twiddle W64^{n1*k2} = Wt[2*n1*k2]. 1024 tasks.
    for (int task = tid; task < 1024; task += 512){
        int y = task >> 3, n1 = task & 7;
        c32 v[8];
        #pragma unroll
        for (int n2 = 0; n2 < 8; ++n2) v[n2] = S[y*65 + n1 + 8*n2];
        fftN<8>(v, twb);
        #pragma unroll
        for (int k2 = 0; k2 < 8; ++k2)
            S[y*65 + n1 + 8*k2] = (n1 && k2) ? cmulc(Wt[2*n1*k2], v[k2]) : v[k2];
    }
    __syncthreads();
    // row IFFT-64 stage2: FFT8 over n1 (slots 8k2..8k2+7) -> slots k2+8*k1.
    // 1024 tasks, r/s/w.
    {
        c32 g0[8], g1[8];
        const int t1 = tid + 512;
        {
            int y = tid >> 3, k2 = tid & 7;
            #pragma unroll
            for (int n1 = 0; n1 < 8; ++n1) g0[n1] = S[y*65 + 8*k2 + n1];
            fftN<8>(g0, twb);
        }
        {
            int y = t1 >> 3, k2 = t1 & 7;
            #pragma unroll
            for (int n1 = 0; n1 < 8; ++n1) g1[n1] = S[y*65 + 8*k2 + n1];
            fftN<8>(g1, twb);
        }
        __syncthreads();
        {
            int y = tid >> 3, k2 = tid & 7;
            #pragma unroll
            for (int k1 = 0; k1 < 8; ++k1) S[y*65 + k2 + 8*k1] = g0[k1];
        }
        {
            int y = t1 >> 3, k2 = t1 & 7;
            #pragma unroll
            for (int k1 = 0; k1 < 8; ++k1) S[y*65 + k2 + 8*k1] = g1[k1];
        }
    }
    __syncthreads();
    // emit: x[2m] = Re z, x[2m+1] = Im z, scale 1/8192
    float* dst = out + (size_t)bt * 49152 + c;
    const float sc = 1.0f / 8192.0f;
    for (int p = tid; p < 8192; p += 512){
        int y = p >> 6, m = p & 63;
        c32 z = S[y*65 + m];
        dst[(size_t)((y << 7) + 2*m    ) * 3] = z.x * sc;
        dst[(size_t)((y << 7) + 2*m + 1) * 3] = z.y * sc;
    }
}

// ---------------------------------------------------------------------------
extern "C" void kernel_launch(void* const* d_in, const int* in_sizes, int n_in,
                              void* d_out, int out_size, void* d_ws, size_t ws_size,
                              hipStream_t stream)
{
    (void)in_sizes; (void)n_in; (void)out_size; (void)ws_size;
    const float* in   = (const float*)d_in[0];
    const float* cw   = (const float*)d_in[1];
    const float* cb   = (const float*)d_in[2];
    const float* wA   = (const float*)d_in[3];
    const float* bA   = (const float*)d_in[4];
    const float* wD   = (const float*)d_in[5];
    const float* bD   = (const float*)d_in[6];
    const float* wM   = (const float*)d_in[7];
    const float* bM   = (const float*)d_in[8];
    const float* wG   = (const float*)d_in[9];
    const float* bG   = (const float*)d_in[10];
    const float* kex  = (const float*)d_in[11];
    const float* kin  = (const float*)d_in[12];
    float* out = (float*)d_out;
    float* ws  = (float*)d_ws;

    float* part = ws;                    // 4096*32            = 131072
    float* gA   = ws + 131072;           // 384
    float* gD   = gA + 384;
    float* gM   = gD + 384;
    float* gG   = gM + 384;              // ends 132608
    float* KEw  = ws + 132608;           // 3*128*65*2         = 49920
    float* KIw  = KEw + 49920;           // ends 232448
    float* U    = ws + 232448;           // 128*3*128*65*2     = 6389760
    float* Yb   = U + 6389760;           // 6389760 (scan output, no alias)

    k_conv   <<<dim3(4096), dim3(512), 0, stream>>>(in, cw, cb, part);
    k_small  <<<dim3(197),  dim3(256), 0, stream>>>(part, wA, bA, wD, bD, wM, bM, wG, bG,
                                                    gA, gD, gM, gG, kex, kin, KEw, KIw);
    k_fft_fwd<<<dim3(384),  dim3(512), 0, stream>>>(in, U);
    k_scan   <<<dim3(390),  dim3(256), 0, stream>>>(U, Yb, KEw, KIw, gA, gD, gM, gG);
    k_fft_inv<<<dim3(384),  dim3(512), 0, stream>>>(Yb, out);
}

// Round 11
// 106.523 us; speedup vs baseline: 2.4684x; 2.4684x over previous
//
#include <hip/hip_runtime.h>
#include <math.h>

typedef float2 c32;

__device__ __forceinline__ c32 cmulc(c32 a, c32 b){
    return make_float2(fmaf(a.x, b.x, -(a.y*b.y)), fmaf(a.x, b.y, a.y*b.x));
}
__device__ __forceinline__ c32 caddc(c32 a, c32 b){ return make_float2(a.x+b.x, a.y+b.y); }
__device__ __forceinline__ c32 csubc(c32 a, c32 b){ return make_float2(a.x-b.x, a.y-b.y); }

// In-register DIT FFT of size N (8 or 16), natural-order in/out.
// tw[m] = e^{sign*2*pi*i*m/16}  (sign baked into the table the caller built).
template<int N>
__device__ __forceinline__ void fftN(c32* a, const c32* tw){
    constexpr int LOG = (N == 16) ? 4 : 3;
    c32 b[N];
    #pragma unroll
    for (int i = 0; i < N; ++i){
        int r = 0;
        #pragma unroll
        for (int bb = 0; bb < LOG; ++bb) r = (r << 1) | ((i >> bb) & 1);
        b[i] = a[r];
    }
    #pragma unroll
    for (int len = 2; len <= N; len <<= 1){
        #pragma unroll
        for (int i = 0; i < N; i += len){
            #pragma unroll
            for (int j = 0; j < len/2; ++j){
                c32 t = b[i + j + len/2];
                if (j) t = cmulc(tw[j * (16/len)], t);
                c32 u = b[i + j];
                b[i + j]         = caddc(u, t);
                b[i + j + len/2] = csubc(u, t);
            }
        }
    }
    #pragma unroll
    for (int i = 0; i < N; ++i) a[i] = b[i];
}

// ---------------------------------------------------------------------------
// 1) conv3x3 stride2 SAME + gelu + partial spatial sums (deterministic)
//    grid = 128 frames x 16 stripes (4 output rows), 256 thr.
//    LDS slab staged as float4; taps are 9 contiguous LDS floats per row.
//    Thread = one output position, all 32 channels; weights via SGPR
//    broadcast.  Reduction: shfl pre-reduce (4:1) then small LDS transpose
//    (total LDS ~24 KB -> 6 blocks/CU, ~75% occupancy).
//    part[(bt*16+sr)*32 + c] = stripe partial sum of gelu(conv)
// ---------------------------------------------------------------------------
__global__ __launch_bounds__(256) void k_conv(const float* __restrict__ in,
                                              const float* __restrict__ cw,
                                              const float* __restrict__ cb,
                                              float* __restrict__ part)
{
    __shared__ float xs[9 * 392];          // rows r0..r0+8, float-cols 0..391
    __shared__ float red[64 * 33];         // [wave*16+lane][ch] pitch 33
    __shared__ float red2[8 * 33];         // [rowgroup][ch]
    const int tid = threadIdx.x;           // 0..255
    const int bt  = blockIdx.x >> 4;
    const int sr  = blockIdx.x & 15;
    const int r0  = 8 * sr;                // first input row of the stripe

    // stage slab as float4: 9 rows x 98 float4 (cols 384..391 zero, plus
    // rows past the bottom zero).  src rows are 384 floats = 96 float4.
    const float4* src4 = (const float4*)(in + (size_t)bt * 49152 + (size_t)r0 * 384);
    const float4 z4 = make_float4(0.f, 0.f, 0.f, 0.f);
    for (int i = tid; i < 9 * 98; i += 256){
        int r = i / 98, c4 = i - r * 98;
        float4 v = z4;
        if (c4 < 96 && (r0 + r) < 128) v = src4[r * 96 + c4];
        *(float4*)&xs[r * 392 + c4 * 4] = v;
    }
    __syncthreads();

    const int oyl = tid >> 6;              // local output row 0..3
    const int ox  = tid & 63;              // output col

    // taps: 3 rows x 9 contiguous floats starting at float-col 6*ox
    float f[27];
    #pragma unroll
    for (int ky = 0; ky < 3; ++ky){
        const int rb = (2 * oyl + ky) * 392 + 6 * ox;
        #pragma unroll
        for (int j = 0; j < 9; ++j) f[ky * 9 + j] = xs[rb + j];
    }

    // 32-channel accumulation; cw/cb reads are uniform -> SGPR broadcast
    float s[32];
    #pragma unroll
    for (int ch = 0; ch < 32; ++ch) s[ch] = cb[ch];
    #pragma unroll
    for (int q = 0; q < 27; ++q){
        const float fv = f[q];
        #pragma unroll
        for (int ch = 0; ch < 32; ++ch)
            s[ch] = fmaf(fv, cw[q*32 + ch], s[ch]);
    }

    // gelu (fast tanh via exp2/rcp) in place
    #pragma unroll
    for (int ch = 0; ch < 32; ++ch){
        const float v  = s[ch];
        const float u_ = 0.7978845608028654f * fmaf(0.044715f * v, v * v, v);
        const float e_ = __builtin_amdgcn_exp2f(2.8853900817779268f * u_);
        const float t_ = 1.0f - 2.0f * __builtin_amdgcn_rcpf(1.0f + e_);
        s[ch] = 0.5f * v * (1.0f + t_);
    }

    // shfl pre-reduce over positions (positions just sum): 4:1 within wave
    #pragma unroll
    for (int ch = 0; ch < 32; ++ch){
        s[ch] += __shfl_down(s[ch], 32, 64);
        s[ch] += __shfl_down(s[ch], 16, 64);
    }
    const int wave = tid >> 6, lane = tid & 63;
    if (lane < 16){
        #pragma unroll
        for (int ch = 0; ch < 32; ++ch)
            red[(wave * 16 + lane) * 33 + ch] = s[ch];
    }
    __syncthreads();

    // stage 1: thread (grp,ch) sums 8 of the 64 rows -> red2[grp][ch]
    {
        const int grp = tid >> 5, ch = tid & 31;   // grp 0..7
        float acc = 0.0f;
        #pragma unroll
        for (int j = 0; j < 8; ++j)
            acc += red[(grp * 8 + j) * 33 + ch];
        red2[grp * 33 + ch] = acc;
    }
    __syncthreads();
    // stage 2: 32 threads sum the 8 row-groups
    if (tid < 32){
        float acc = 0.0f;
        #pragma unroll
        for (int g2 = 0; g2 < 8; ++g2) acc += red2[g2 * 33 + tid];
        part[(size_t)blockIdx.x * 32 + tid] = acc;
    }
}

// ---------------------------------------------------------------------------
// 2) gates, parallel two-stage: one block per bt (128 blocks, 256 thr).
//    Threads (qg,j) sum 2 stripes each (coalesced) -> LDS tree over qg ->
//    ctx[32] -> 12 threads compute the four 32-tap gate dot-products.
//    Replaces the old 6-block straggler (512 serial loads/thread, ~38 us).
// ---------------------------------------------------------------------------
__global__ __launch_bounds__(256) void k_gates(const float* __restrict__ part,
    const float* __restrict__ wA, const float* __restrict__ bA,
    const float* __restrict__ wD, const float* __restrict__ bD,
    const float* __restrict__ wM, const float* __restrict__ bM,
    const float* __restrict__ wG, const float* __restrict__ bG,
    float* __restrict__ gA, float* __restrict__ gD,
    float* __restrict__ gM, float* __restrict__ gG)
{
    __shared__ float red[8 * 33];
    __shared__ float ctx[32];
    const int tid = threadIdx.x;
    const int bt  = blockIdx.x;            // 0..127
    const int j   = tid & 31, qg = tid >> 5;   // qg 0..7

    float acc = part[((size_t)(bt * 16 + 2 * qg    )) * 32 + j]
              + part[((size_t)(bt * 16 + 2 * qg + 1)) * 32 + j];
    red[qg * 33 + j] = acc;
    __syncthreads();
    if (tid < 32){
        float s = 0.f;
        #pragma unroll
        for (int q = 0; q < 8; ++q) s += red[q * 33 + tid];
        ctx[tid] = s * (1.0f / 4096.0f);
    }
    __syncthreads();
    if (tid < 12){
        const int gate = tid / 3, c = tid % 3;
        const float* w = (gate == 0) ? wA : (gate == 1) ? wD : (gate == 2) ? wM : wG;
        const float* b = (gate == 0) ? bA : (gate == 1) ? bD : (gate == 2) ? bM : bG;
        float s = b[c];
        #pragma unroll
        for (int jj = 0; jj < 32; ++jj) s = fmaf(ctx[jj], w[jj * 3 + c], s);
        const int o = bt * 3 + c;
        if (gate < 2){
            float v = 1.0f / (1.0f + expf(-s));
            ((gate == 0) ? gA : gD)[o] = v;
        } else {
            float v = fmaxf(s, 0.f) + log1pf(expf(-fabsf(s)));
            ((gate == 2) ? gM : gG)[o] = v;
        }
    }
}

// ---------------------------------------------------------------------------
// 3) spectral kernels: KE/KI[c][u][v] = rfft2(pad(k, 56)) via direct 256-tap DFT
// ---------------------------------------------------------------------------
__global__ __launch_bounds__(256) void k_spectral(const float* __restrict__ k_exc,
                                                  const float* __restrict__ k_inh,
                                                  float* __restrict__ KEw,
                                                  float* __restrict__ KIw)
{
    __shared__ c32 Wt[128];
    int tid = threadIdx.x;
    if (tid < 128){
        float ang = -0.049087385212340517f * (float)tid;   // -2*pi*t/128
        float s, co; sincosf(ang, &s, &co);
        Wt[tid] = make_float2(co, s);
    }
    __syncthreads();
    int g = blockIdx.x * 256 + tid;
    if (g >= 2 * 24960) return;
    int which = g / 24960, r = g % 24960;
    int c = r / 8320, uv = r % 8320;
    int u_ = uv / 65, v_ = uv % 65;
    const float* kk = which ? k_inh : k_exc;
    float ar = 0.f, ai = 0.f;
    for (int y = 0; y < 16; ++y){
        int pu = u_ * (56 + y);
        #pragma unroll
        for (int x = 0; x < 16; ++x){
            int idx = (pu + v_ * (56 + x)) & 127;
            float kv = kk[(y*16 + x)*3 + c];
            c32 w = Wt[idx];
            ar = fmaf(kv, w.x, ar);
            ai = fmaf(kv, w.y, ai);
        }
    }
    ((float2*)(which ? KIw : KEw))[c*8320 + uv] = make_float2(ar, ai);
}

// ---------------------------------------------------------------------------
// 4) forward rfft2 per (b,t,c) image.  Single 65KB LDS buffer (2 blocks/CU).
//    FFT-128 = radix-16 (in-place, task-owned slots) then radix-8
//    (read-all -> barrier -> write-all).  Hermitian unpack same-buffer.
// ---------------------------------------------------------------------------
__global__ __launch_bounds__(512, 4) void k_fft_fwd(const float* __restrict__ in,
                                                    float* __restrict__ U_ws)
{
    __shared__ c32 S[8320];                 // rows: [64][130]; cols: [128][65]
    __shared__ c32 Wt[128];                 // e^{-2 pi i t/128}
    const int tid = threadIdx.x;
    const int img = blockIdx.x;             // bt*3 + c
    const int bt = img / 3, c = img % 3;

    if (tid < 128){
        float ang = -0.049087385212340517f * (float)tid;
        float s, co; sincosf(ang, &s, &co);
        Wt[tid] = make_float2(co, s);
    }
    __syncthreads();
    c32 twb[8];
    #pragma unroll
    for (int m = 0; m < 8; ++m) twb[m] = Wt[8*m];   // 16th roots (serves FFT8 too)

    // pack: S[r*130+x] = in[2r][x] + i*in[2r+1][x]
    const float* src = in + (size_t)bt * 49152 + c;
    for (int p = tid; p < 8192; p += 512){
        int r = p >> 7, x = p & 127;
        float re = src[(size_t)((2*r)   * 128 + x) * 3];
        float im = src[(size_t)((2*r+1) * 128 + x) * 3];
        S[r*130 + x] = make_float2(re, im);
    }
    __syncthreads();

    // row stage1: FFT16 over n2 at slots n1+8*n2 (task-owned, in place),
    // then twiddle W128^{n1*k2}.  512 tasks = 512 threads.
    {
        int r = tid >> 3, n1 = tid & 7;
        c32 v[16];
        #pragma unroll
        for (int n2 = 0; n2 < 16; ++n2) v[n2] = S[r*130 + n1 + 8*n2];
        fftN<16>(v, twb);
        #pragma unroll
        for (int k2 = 0; k2 < 16; ++k2)
            S[r*130 + n1 + 8*k2] = (n1 && k2) ? cmulc(Wt[n1*k2], v[k2]) : v[k2];
    }
    __syncthreads();
    // row stage2: FFT8 over n1 (slots 8k2..8k2+7) -> slots k2+16*k1.
    // 1024 tasks, read-all/sync/write-all.
    {
        c32 g0[8], g1[8];
        const int t1 = tid + 512;
        {
            int r = tid >> 4, k2 = tid & 15;
            #pragma unroll
            for (int n1 = 0; n1 < 8; ++n1) g0[n1] = S[r*130 + 8*k2 + n1];
            fftN<8>(g0, twb);
        }
        {
            int r = t1 >> 4, k2 = t1 & 15;
            #pragma unroll
            for (int n1 = 0; n1 < 8; ++n1) g1[n1] = S[r*130 + 8*k2 + n1];
            fftN<8>(g1, twb);
        }
        __syncthreads();
        {
            int r = tid >> 4, k2 = tid & 15;
            #pragma unroll
            for (int k1 = 0; k1 < 8; ++k1) S[r*130 + k2 + 16*k1] = g0[k1];
        }
        {
            int r = t1 >> 4, k2 = t1 & 15;
            #pragma unroll
            for (int k1 = 0; k1 < 8; ++k1) S[r*130 + k2 + 16*k1] = g1[k1];
        }
    }
    __syncthreads();
    // unpack packed real rows -> C[128][65] layout, same buffer.
    // 4160 tasks; read-all/sync/write-all (<=9 tasks/thread).
    {
        c32 e0[9], e1[9];
        #pragma unroll
        for (int j = 0; j < 9; ++j){
            int task = tid + 512*j;
            if (task < 4160){
                int r = task / 65, v_ = task % 65;
                c32 zk = S[r*130 + v_];
                c32 zn = S[r*130 + ((128 - v_) & 127)];
                e0[j] = make_float2(0.5f*(zk.x + zn.x),  0.5f*(zk.y - zn.y));
                e1[j] = make_float2(0.5f*(zk.y + zn.y), -0.5f*(zk.x - zn.x));
            }
        }
        __syncthreads();
        #pragma unroll
        for (int j = 0; j < 9; ++j){
            int task = tid + 512*j;
            if (task < 4160){
                int r = task / 65, v_ = task % 65;
                S[(2*r)  *65 + v_] = e0[j];
                S[(2*r+1)*65 + v_] = e1[j];
            }
        }
    }
    __syncthreads();
    // col stage1: FFT16 over n2 at rows n1+8*n2 (task-owned), twiddle. 520 tasks.
    for (int task = tid; task < 520; task += 512){
        int n1 = task / 65, v_ = task % 65;
        c32 v[16];
        #pragma unroll
        for (int n2 = 0; n2 < 16; ++n2) v[n2] = S[(n1 + 8*n2)*65 + v_];
        fftN<16>(v, twb);
        #pragma unroll
        for (int k2 = 0; k2 < 16; ++k2)
            S[(n1 + 8*k2)*65 + v_] = (n1 && k2) ? cmulc(Wt[n1*k2], v[k2]) : v[k2];
    }
    __syncthreads();
    // col stage2: FFT8 over n1 (rows 8k2..8k2+7) -> rows k2+16*k1. 1040 tasks.
    {
        c32 g0[8], g1[8], g2[8];
        const int t1 = tid + 512, t2 = tid + 1024;
        {
            int k2 = tid / 65, v_ = tid % 65;
            #pragma unroll
            for (int n1 = 0; n1 < 8; ++n1) g0[n1] = S[(8*k2 + n1)*65 + v_];
            fftN<8>(g0, twb);
        }
        {
            int k2 = t1 / 65, v_ = t1 % 65;
            #pragma unroll
            for (int n1 = 0; n1 < 8; ++n1) g1[n1] = S[(8*k2 + n1)*65 + v_];
            fftN<8>(g1, twb);
        }
        if (t2 < 1040){
            int k2 = t2 / 65, v_ = t2 % 65;
            #pragma unroll
            for (int n1 = 0; n1 < 8; ++n1) g2[n1] = S[(8*k2 + n1)*65 + v_];
            fftN<8>(g2, twb);
        }
        __syncthreads();
        {
            int k2 = tid / 65, v_ = tid % 65;
            #pragma unroll
            for (int k1 = 0; k1 < 8; ++k1) S[(k2 + 16*k1)*65 + v_] = g0[k1];
        }
        {
            int k2 = t1 / 65, v_ = t1 % 65;
            #pragma unroll
            for (int k1 = 0; k1 < 8; ++k1) S[(k2 + 16*k1)*65 + v_] = g1[k1];
        }
        if (t2 < 1040){
            int k2 = t2 / 65, v_ = t2 % 65;
            #pragma unroll
            for (int k1 = 0; k1 < 8; ++k1) S[(k2 + 16*k1)*65 + v_] = g2[k1];
        }
    }
    __syncthreads();
    float2* dst = ((float2*)U_ws) + (size_t)img * 8320;
    for (int p = tid; p < 8320; p += 512) dst[p] = S[p];
}

// ---------------------------------------------------------------------------
// 5) sequential T-scan, U -> Y (separate buffers; compiler hoists U loads).
//    x' = 0.9a*x + (-KI*mu)*y + U ; y' = (KE*ga)*x + 0.9d*y.
// ---------------------------------------------------------------------------
__global__ __launch_bounds__(256) void k_scan(const float* __restrict__ U,
    float* __restrict__ Y,
    const float* __restrict__ KEw, const float* __restrict__ KIw,
    const float* __restrict__ gA, const float* __restrict__ gD,
    const float* __restrict__ gM, const float* __restrict__ gG)
{
    int g = blockIdx.x * 256 + threadIdx.x;
    if (g >= 4*3*128*65) return;
    int b = g / 24960, r = g % 24960;
    int c = r / 8320, uv = r % 8320;
    float2 ke = ((const float2*)KEw)[c*8320 + uv];
    float2 ki = ((const float2*)KIw)[c*8320 + uv];
    const float2* Up = (const float2*)U;
    float2* Yp = (float2*)Y;
    float xr = 0.f, xi = 0.f, yr = 0.f, yi = 0.f;
    #pragma unroll
    for (int t = 0; t < 32; ++t){
        int btc = (b*32 + t)*3 + c;
        float al = 0.9f * gA[btc], de = 0.9f * gD[btc];
        float mu = gM[btc],       ga = gG[btc];
        float axr = -ki.x * mu, axi = -ki.y * mu;
        float ayr =  ke.x * ga, ayi =  ke.y * ga;
        size_t iu = (size_t)btc * 8320 + uv;
        float2 uin = Up[iu];
        float nxr = fmaf(al, xr, fmaf(axr, yr, fmaf(-axi, yi, uin.x)));
        float nxi = fmaf(al, xi, fmaf(axr, yi, fmaf( axi, yr, uin.y)));
        float nyr = fmaf(ayr, xr, fmaf(-ayi, xi, de * yr));
        float nyi = fmaf(ayr, xi, fmaf( ayi, xr, de * yi));
        Yp[iu] = make_float2(nyr, nyi);
        xr = nxr; xi = nxi; yr = nyr; yi = nyi;
    }
}

// ---------------------------------------------------------------------------
// 6) inverse rfft2, single 65KB LDS buffer (2 blocks/CU).
//    col IFFT-128 (radix-16 in-place + radix-8 r/s/w), Hermitian EO-prep
//    paired-task in-place, row IFFT-64 (radix-8 in-place + radix-8 r/s/w).
// ---------------------------------------------------------------------------
__global__ __launch_bounds__(512, 4) void k_fft_inv(const float* __restrict__ Y_ws,
                                                    float* __restrict__ out)
{
    __shared__ c32 S[8320];                 // [128][65]
    __shared__ c32 Wt[128];                 // e^{+2 pi i t/128}
    const int tid = threadIdx.x;
    const int img = blockIdx.x;
    const int bt = img / 3, c = img % 3;

    if (tid < 128){
        float ang = 0.049087385212340517f * (float)tid;
        float s, co; sincosf(ang, &s, &co);
        Wt[tid] = make_float2(co, s);
    }
    __syncthreads();
    c32 twb[8];
    #pragma unroll
    for (int m = 0; m < 8; ++m) twb[m] = Wt[8*m];

    const float2* srcv = ((const float2*)Y_ws) + (size_t)img * 8320;
    for (int p = tid; p < 8320; p += 512) S[p] = srcv[p];
    __syncthreads();

    // col IFFT stage1: FFT16 over n2 at rows n1+8*n2 (task-owned). 520 tasks.
    for (int task = tid; task < 520; task += 512){
        int n1 = task / 65, v_ = task % 65;
        c32 v[16];
        #pragma unroll
        for (int n2 = 0; n2 < 16; ++n2) v[n2] = S[(n1 + 8*n2)*65 + v_];
        fftN<16>(v, twb);
        #pragma unroll
        for (int k2 = 0; k2 < 16; ++k2)
            S[(n1 + 8*k2)*65 + v_] = (n1 && k2) ? cmulc(Wt[n1*k2], v[k2]) : v[k2];
    }
    __syncthreads();
    // col IFFT stage2: FFT8 over n1 -> rows k2+16*k1. 1040 tasks, r/s/w.
    {
        c32 g0[8], g1[8], g2[8];
        const int t1 = tid + 512, t2 = tid + 1024;
        {
            int k2 = tid / 65, v_ = tid % 65;
            #pragma unroll
            for (int n1 = 0; n1 < 8; ++n1) g0[n1] = S[(8*k2 + n1)*65 + v_];
            fftN<8>(g0, twb);
        }
        {
            int k2 = t1 / 65, v_ = t1 % 65;
            #pragma unroll
            for (int n1 = 0; n1 < 8; ++n1) g1[n1] = S[(8*k2 + n1)*65 + v_];
            fftN<8>(g1, twb);
        }
        if (t2 < 1040){
            int k2 = t2 / 65, v_ = t2 % 65;
            #pragma unroll
            for (int n1 = 0; n1 < 8; ++n1) g2[n1] = S[(8*k2 + n1)*65 + v_];
            fftN<8>(g2, twb);
        }
        __syncthreads();
        {
            int k2 = tid / 65, v_ = tid % 65;
            #pragma unroll
            for (int k1 = 0; k1 < 8; ++k1) S[(k2 + 16*k1)*65 + v_] = g0[k1];
        }
        {
            int k2 = t1 / 65, v_ = t1 % 65;
            #pragma unroll
            for (int k1 = 0; k1 < 8; ++k1) S[(k2 + 16*k1)*65 + v_] = g1[k1];
        }
        if (t2 < 1040){
            int k2 = t2 / 65, v_ = t2 % 65;
            #pragma unroll
            for (int k1 = 0; k1 < 8; ++k1) S[(k2 + 16*k1)*65 + v_] = g2[k1];
        }
    }
    __syncthreads();
    // EO prep: paired tasks (k, 64-k) per row -> in-place. 128*33 tasks.
    // Z[k] = E[k] + i*O[k]; numpy drops imag of bins 0,64.
    for (int task = tid; task < 128*33; task += 512){
        int y = task / 33, k = task % 33;
        c32 Xk = S[y*65 + k];
        c32 Xn = S[y*65 + 64 - k];
        if (k == 0){ Xk.y = 0.f; Xn.y = 0.f; }
        float Er = 0.5f*(Xk.x + Xn.x), Ei = 0.5f*(Xk.y - Xn.y);
        c32 d  = make_float2(0.5f*(Xk.x - Xn.x), 0.5f*(Xk.y + Xn.y));
        c32 O  = cmulc(Wt[k], d);
        S[y*65 + k] = make_float2(Er - O.y, Ei + O.x);
        if (k > 0 && k < 32){
            float Er2 = 0.5f*(Xn.x + Xk.x), Ei2 = 0.5f*(Xn.y - Xk.y);
            c32 d2 = make_float2(0.5f*(Xn.x - Xk.x), 0.5f*(Xn.y + Xk.y));
            c32 O2 = cmulc(Wt[64 - k], d2);
            S[y*65 + 64 - k] = make_float2(Er2 - O2.y, Ei2 + O2.x);
        }
    }
    __syncthreads();
    // row IFFT-64 stage1: FFT8 over n2 at slots n1+8*n2 (task-owned),
    // twiddle W64^{n1*k2} = Wt[2*n1*k2]. 1024 tasks.
    for (int task = tid; task < 1024; task += 512){
        int y = task >> 3, n1 = task & 7;
        c32 v[8];
        #pragma unroll
        for (int n2 = 0; n2 < 8; ++n2) v[n2] = S[y*65 + n1 + 8*n2];
        fftN<8>(v, twb);
        #pragma unroll
        for (int k2 = 0; k2 < 8; ++k2)
            S[y*65 + n1 + 8*k2] = (n1 && k2) ? cmulc(Wt[2*n1*k2], v[k2]) : v[k2];
    }
    __syncthreads();
    // row IFFT-64 stage2: FFT8 over n1 (slots 8k2..8k2+7) -> slots k2+8*k1.
    // 1024 tasks, r/s/w.
    {
        c32 g0[8], g1[8];
        const int t1 = tid + 512;
        {
            int y = tid >> 3, k2 = tid & 7;
            #pragma unroll
            for (int n1 = 0; n1 < 8; ++n1) g0[n1] = S[y*65 + 8*k2 + n1];
            fftN<8>(g0, twb);
        }
        {
            int y = t1 >> 3, k2 = t1 & 7;
            #pragma unroll
            for (int n1 = 0; n1 < 8; ++n1) g1[n1] = S[y*65 + 8*k2 + n1];
            fftN<8>(g1, twb);
        }
        __syncthreads();
        {
            int y = tid >> 3, k2 = tid & 7;
            #pragma unroll
            for (int k1 = 0; k1 < 8; ++k1) S[y*65 + k2 + 8*k1] = g0[k1];
        }
        {
            int y = t1 >> 3, k2 = t1 & 7;
            #pragma unroll
            for (int k1 = 0; k1 < 8; ++k1) S[y*65 + k2 + 8*k1] = g1[k1];
        }
    }
    __syncthreads();
    // emit: x[2m] = Re z, x[2m+1] = Im z, scale 1/8192
    float* dst = out + (size_t)bt * 49152 + c;
    const float sc = 1.0f / 8192.0f;
    for (int p = tid; p < 8192; p += 512){
        int y = p >> 6, m = p & 63;
        c32 z = S[y*65 + m];
        dst[(size_t)((y << 7) + 2*m    ) * 3] = z.x * sc;
        dst[(size_t)((y << 7) + 2*m + 1) * 3] = z.y * sc;
    }
}

// ---------------------------------------------------------------------------
extern "C" void kernel_launch(void* const* d_in, const int* in_sizes, int n_in,
                              void* d_out, int out_size, void* d_ws, size_t ws_size,
                              hipStream_t stream)
{
    (void)in_sizes; (void)n_in; (void)out_size; (void)ws_size;
    const float* in   = (const float*)d_in[0];
    const float* cw   = (const float*)d_in[1];
    const float* cb   = (const float*)d_in[2];
    const float* wA   = (const float*)d_in[3];
    const float* bA   = (const float*)d_in[4];
    const float* wD   = (const float*)d_in[5];
    const float* bD   = (const float*)d_in[6];
    const float* wM   = (const float*)d_in[7];
    const float* bM   = (const float*)d_in[8];
    const float* wG   = (const float*)d_in[9];
    const float* bG   = (const float*)d_in[10];
    const float* kex  = (const float*)d_in[11];
    const float* kin  = (const float*)d_in[12];
    float* out = (float*)d_out;
    float* ws  = (float*)d_ws;

    float* part = ws;                    // 2048*32            = 65536
    float* gA   = ws + 65536;            // 384
    float* gD   = gA + 384;
    float* gM   = gD + 384;
    float* gG   = gM + 384;              // ends 67072
    float* KEw  = ws + 67072;            // 3*128*65*2         = 49920
    float* KIw  = KEw + 49920;           // ends 166912
    float* U    = ws + 166912;           // 128*3*128*65*2     = 6389760
    float* Yb   = U + 6389760;           // 6389760 (scan output, no alias)

    k_conv    <<<dim3(2048), dim3(256), 0, stream>>>(in, cw, cb, part);
    k_gates   <<<dim3(128),  dim3(256), 0, stream>>>(part, wA, bA, wD, bD, wM, bM, wG, bG,
                                                     gA, gD, gM, gG);
    k_spectral<<<dim3(195),  dim3(256), 0, stream>>>(kex, kin, KEw, KIw);
    k_fft_fwd <<<dim3(384),  dim3(512), 0, stream>>>(in, U);
    k_scan    <<<dim3(390),  dim3(256), 0, stream>>>(U, Yb, KEw, KIw, gA, gD, gM, gG);
    k_fft_inv <<<dim3(384),  dim3(512), 0, stream>>>(Yb, out);
}

// Round 12
// 94.485 us; speedup vs baseline: 2.7829x; 1.1274x over previous
//
#include <hip/hip_runtime.h>
#include <math.h>

typedef float2 c32;

__device__ __forceinline__ c32 cmulc(c32 a, c32 b){
    return make_float2(fmaf(a.x, b.x, -(a.y*b.y)), fmaf(a.x, b.y, a.y*b.x));
}
__device__ __forceinline__ c32 caddc(c32 a, c32 b){ return make_float2(a.x+b.x, a.y+b.y); }
__device__ __forceinline__ c32 csubc(c32 a, c32 b){ return make_float2(a.x-b.x, a.y-b.y); }

// In-register DIT FFT of size N (8 or 16), natural-order in/out.
// tw[m] = e^{sign*2*pi*i*m/16}  (sign baked into the table the caller built).
template<int N>
__device__ __forceinline__ void fftN(c32* a, const c32* tw){
    constexpr int LOG = (N == 16) ? 4 : 3;
    c32 b[N];
    #pragma unroll
    for (int i = 0; i < N; ++i){
        int r = 0;
        #pragma unroll
        for (int bb = 0; bb < LOG; ++bb) r = (r << 1) | ((i >> bb) & 1);
        b[i] = a[r];
    }
    #pragma unroll
    for (int len = 2; len <= N; len <<= 1){
        #pragma unroll
        for (int i = 0; i < N; i += len){
            #pragma unroll
            for (int j = 0; j < len/2; ++j){
                c32 t = b[i + j + len/2];
                if (j) t = cmulc(tw[j * (16/len)], t);
                c32 u = b[i + j];
                b[i + j]         = caddc(u, t);
                b[i + j + len/2] = csubc(u, t);
            }
        }
    }
    #pragma unroll
    for (int i = 0; i < N; ++i) a[i] = b[i];
}

// ---------------------------------------------------------------------------
// 1) merged: blocks 0..2047 = conv3x3 stride2 + gelu + stripe partial sums
//    (identical to R11 k_conv); blocks 2048.. = spectral rfft2 of padded
//    k_exc/k_inh (direct 256-tap DFT; backfills CUs as conv retires).
// ---------------------------------------------------------------------------
__global__ __launch_bounds__(256) void k_conv_spec(const float* __restrict__ in,
                                                   const float* __restrict__ cw,
                                                   const float* __restrict__ cb,
                                                   float* __restrict__ part,
                                                   const float* __restrict__ k_exc,
                                                   const float* __restrict__ k_inh,
                                                   float* __restrict__ KEw,
                                                   float* __restrict__ KIw)
{
    __shared__ float xs[9 * 392];          // conv: slab rows r0..r0+8
    __shared__ float red[64 * 33];         // conv: [wave*16+lane][ch]
    __shared__ float red2[8 * 33];         // conv: [rowgroup][ch]
    __shared__ c32 Wt[128];                // spectral: twiddles
    const int tid = threadIdx.x;

    if (blockIdx.x >= 2048){
        // ---- spectral branch ----
        if (tid < 128){
            float ang = -0.049087385212340517f * (float)tid;   // -2*pi*t/128
            float s, co; sincosf(ang, &s, &co);
            Wt[tid] = make_float2(co, s);
        }
        __syncthreads();
        int g = (blockIdx.x - 2048) * 256 + tid;
        if (g >= 2 * 24960) return;
        int which = g / 24960, r = g % 24960;
        int c = r / 8320, uv = r % 8320;
        int u_ = uv / 65, v_ = uv % 65;
        const float* kk = which ? k_inh : k_exc;
        float ar = 0.f, ai = 0.f;
        for (int y = 0; y < 16; ++y){
            int pu = u_ * (56 + y);
            #pragma unroll
            for (int x = 0; x < 16; ++x){
                int idx = (pu + v_ * (56 + x)) & 127;
                float kv = kk[(y*16 + x)*3 + c];
                c32 w = Wt[idx];
                ar = fmaf(kv, w.x, ar);
                ai = fmaf(kv, w.y, ai);
            }
        }
        ((float2*)(which ? KIw : KEw))[c*8320 + uv] = make_float2(ar, ai);
        return;
    }

    // ---- conv branch ----
    const int bt  = blockIdx.x >> 4;
    const int sr  = blockIdx.x & 15;
    const int r0  = 8 * sr;                // first input row of the stripe

    const float4* src4 = (const float4*)(in + (size_t)bt * 49152 + (size_t)r0 * 384);
    const float4 z4 = make_float4(0.f, 0.f, 0.f, 0.f);
    for (int i = tid; i < 9 * 98; i += 256){
        int r = i / 98, c4 = i - r * 98;
        float4 v = z4;
        if (c4 < 96 && (r0 + r) < 128) v = src4[r * 96 + c4];
        *(float4*)&xs[r * 392 + c4 * 4] = v;
    }
    __syncthreads();

    const int oyl = tid >> 6;              // local output row 0..3
    const int ox  = tid & 63;              // output col

    float f[27];
    #pragma unroll
    for (int ky = 0; ky < 3; ++ky){
        const int rb = (2 * oyl + ky) * 392 + 6 * ox;
        #pragma unroll
        for (int j = 0; j < 9; ++j) f[ky * 9 + j] = xs[rb + j];
    }

    float s[32];
    #pragma unroll
    for (int ch = 0; ch < 32; ++ch) s[ch] = cb[ch];
    #pragma unroll
    for (int q = 0; q < 27; ++q){
        const float fv = f[q];
        #pragma unroll
        for (int ch = 0; ch < 32; ++ch)
            s[ch] = fmaf(fv, cw[q*32 + ch], s[ch]);
    }

    #pragma unroll
    for (int ch = 0; ch < 32; ++ch){
        const float v  = s[ch];
        const float u_ = 0.7978845608028654f * fmaf(0.044715f * v, v * v, v);
        const float e_ = __builtin_amdgcn_exp2f(2.8853900817779268f * u_);
        const float t_ = 1.0f - 2.0f * __builtin_amdgcn_rcpf(1.0f + e_);
        s[ch] = 0.5f * v * (1.0f + t_);
    }

    #pragma unroll
    for (int ch = 0; ch < 32; ++ch){
        s[ch] += __shfl_down(s[ch], 32, 64);
        s[ch] += __shfl_down(s[ch], 16, 64);
    }
    const int wave = tid >> 6, lane = tid & 63;
    if (lane < 16){
        #pragma unroll
        for (int ch = 0; ch < 32; ++ch)
            red[(wave * 16 + lane) * 33 + ch] = s[ch];
    }
    __syncthreads();

    {
        const int grp = tid >> 5, ch = tid & 31;   // grp 0..7
        float acc = 0.0f;
        #pragma unroll
        for (int j = 0; j < 8; ++j)
            acc += red[(grp * 8 + j) * 33 + ch];
        red2[grp * 33 + ch] = acc;
    }
    __syncthreads();
    if (tid < 32){
        float acc = 0.0f;
        #pragma unroll
        for (int g2 = 0; g2 < 8; ++g2) acc += red2[g2 * 33 + tid];
        part[(size_t)blockIdx.x * 32 + tid] = acc;
    }
}

// ---------------------------------------------------------------------------
// 2) forward rfft2 (blocks 0..383, identical math to R11) + gates piggyback
//    (blocks 384..511: one bt each; tid<256 active; fits in the same
//    single block-wave since 384+128 = 512 = 256 CUs x 2 blocks/CU).
// ---------------------------------------------------------------------------
__global__ __launch_bounds__(512, 4) void k_fft_fwd(const float* __restrict__ in,
                                                    float* __restrict__ U_ws,
    const float* __restrict__ part,
    const float* __restrict__ wA, const float* __restrict__ bA,
    const float* __restrict__ wD, const float* __restrict__ bD,
    const float* __restrict__ wM, const float* __restrict__ bM,
    const float* __restrict__ wG, const float* __restrict__ bG,
    float* __restrict__ gA, float* __restrict__ gD,
    float* __restrict__ gM, float* __restrict__ gG)
{
    __shared__ c32 S[8320];                 // rows: [64][130]; cols: [128][65]
    __shared__ c32 Wt[128];                 // e^{-2 pi i t/128}
    const int tid = threadIdx.x;

    if (blockIdx.x >= 384){
        // ---- gates branch (parallel two-stage reduction) ----
        float* shred = (float*)S;            // 8*33 floats
        float* ctx   = ((float*)S) + 8 * 33; // 32 floats
        const int bt = blockIdx.x - 384;     // 0..127
        if (tid < 256){
            const int j = tid & 31, qg = tid >> 5;
            float acc = part[((size_t)(bt * 16 + 2 * qg    )) * 32 + j]
                      + part[((size_t)(bt * 16 + 2 * qg + 1)) * 32 + j];
            shred[qg * 33 + j] = acc;
        }
        __syncthreads();
        if (tid < 32){
            float s = 0.f;
            #pragma unroll
            for (int q = 0; q < 8; ++q) s += shred[q * 33 + tid];
            ctx[tid] = s * (1.0f / 4096.0f);
        }
        __syncthreads();
        if (tid < 12){
            const int gate = tid / 3, c = tid % 3;
            const float* w = (gate == 0) ? wA : (gate == 1) ? wD : (gate == 2) ? wM : wG;
            const float* b = (gate == 0) ? bA : (gate == 1) ? bD : (gate == 2) ? bM : bG;
            float s = b[c];
            #pragma unroll
            for (int jj = 0; jj < 32; ++jj) s = fmaf(ctx[jj], w[jj * 3 + c], s);
            const int o = bt * 3 + c;
            if (gate < 2){
                float v = 1.0f / (1.0f + expf(-s));
                ((gate == 0) ? gA : gD)[o] = v;
            } else {
                float v = fmaxf(s, 0.f) + log1pf(expf(-fabsf(s)));
                ((gate == 2) ? gM : gG)[o] = v;
            }
        }
        return;
    }

    // ---- forward FFT branch ----
    const int img = blockIdx.x;             // bt*3 + c
    const int bt = img / 3, c = img % 3;

    if (tid < 128){
        float ang = -0.049087385212340517f * (float)tid;
        float s, co; sincosf(ang, &s, &co);
        Wt[tid] = make_float2(co, s);
    }
    __syncthreads();
    c32 twb[8];
    #pragma unroll
    for (int m = 0; m < 8; ++m) twb[m] = Wt[8*m];   // 16th roots (serves FFT8 too)

    // pack: S[r*130+x] = in[2r][x] + i*in[2r+1][x]
    const float* src = in + (size_t)bt * 49152 + c;
    for (int p = tid; p < 8192; p += 512){
        int r = p >> 7, x = p & 127;
        float re = src[(size_t)((2*r)   * 128 + x) * 3];
        float im = src[(size_t)((2*r+1) * 128 + x) * 3];
        S[r*130 + x] = make_float2(re, im);
    }
    __syncthreads();

    // row stage1: FFT16 over n2 at slots n1+8*n2 (task-owned, in place),
    // then twiddle W128^{n1*k2}.  512 tasks = 512 threads.
    {
        int r = tid >> 3, n1 = tid & 7;
        c32 v[16];
        #pragma unroll
        for (int n2 = 0; n2 < 16; ++n2) v[n2] = S[r*130 + n1 + 8*n2];
        fftN<16>(v, twb);
        #pragma unroll
        for (int k2 = 0; k2 < 16; ++k2)
            S[r*130 + n1 + 8*k2] = (n1 && k2) ? cmulc(Wt[n1*k2], v[k2]) : v[k2];
    }
    __syncthreads();
    // row stage2: FFT8 over n1 (slots 8k2..8k2+7) -> slots k2+16*k1.
    // 1024 tasks, read-all/sync/write-all.
    {
        c32 g0[8], g1[8];
        const int t1 = tid + 512;
        {
            int r = tid >> 4, k2 = tid & 15;
            #pragma unroll
            for (int n1 = 0; n1 < 8; ++n1) g0[n1] = S[r*130 + 8*k2 + n1];
            fftN<8>(g0, twb);
        }
        {
            int r = t1 >> 4, k2 = t1 & 15;
            #pragma unroll
            for (int n1 = 0; n1 < 8; ++n1) g1[n1] = S[r*130 + 8*k2 + n1];
            fftN<8>(g1, twb);
        }
        __syncthreads();
        {
            int r = tid >> 4, k2 = tid & 15;
            #pragma unroll
            for (int k1 = 0; k1 < 8; ++k1) S[r*130 + k2 + 16*k1] = g0[k1];
        }
        {
            int r = t1 >> 4, k2 = t1 & 15;
            #pragma unroll
            for (int k1 = 0; k1 < 8; ++k1) S[r*130 + k2 + 16*k1] = g1[k1];
        }
    }
    __syncthreads();
    // unpack packed real rows -> C[128][65] layout, same buffer.
    // 4160 tasks; read-all/sync/write-all (<=9 tasks/thread).
    {
        c32 e0[9], e1[9];
        #pragma unroll
        for (int j = 0; j < 9; ++j){
            int task = tid + 512*j;
            if (task < 4160){
                int r = task / 65, v_ = task % 65;
                c32 zk = S[r*130 + v_];
                c32 zn = S[r*130 + ((128 - v_) & 127)];
                e0[j] = make_float2(0.5f*(zk.x + zn.x),  0.5f*(zk.y - zn.y));
                e1[j] = make_float2(0.5f*(zk.y + zn.y), -0.5f*(zk.x - zn.x));
            }
        }
        __syncthreads();
        #pragma unroll
        for (int j = 0; j < 9; ++j){
            int task = tid + 512*j;
            if (task < 4160){
                int r = task / 65, v_ = task % 65;
                S[(2*r)  *65 + v_] = e0[j];
                S[(2*r+1)*65 + v_] = e1[j];
            }
        }
    }
    __syncthreads();
    // col stage1: FFT16 over n2 at rows n1+8*n2 (task-owned), twiddle. 520 tasks.
    for (int task = tid; task < 520; task += 512){
        int n1 = task / 65, v_ = task % 65;
        c32 v[16];
        #pragma unroll
        for (int n2 = 0; n2 < 16; ++n2) v[n2] = S[(n1 + 8*n2)*65 + v_];
        fftN<16>(v, twb);
        #pragma unroll
        for (int k2 = 0; k2 < 16; ++k2)
            S[(n1 + 8*k2)*65 + v_] = (n1 && k2) ? cmulc(Wt[n1*k2], v[k2]) : v[k2];
    }
    __syncthreads();
    // col stage2: FFT8 over n1 (rows 8k2..8k2+7) -> rows k2+16*k1. 1040 tasks.
    {
        c32 g0[8], g1[8], g2[8];
        const int t1 = tid + 512, t2 = tid + 1024;
        {
            int k2 = tid / 65, v_ = tid % 65;
            #pragma unroll
            for (int n1 = 0; n1 < 8; ++n1) g0[n1] = S[(8*k2 + n1)*65 + v_];
            fftN<8>(g0, twb);
        }
        {
            int k2 = t1 / 65, v_ = t1 % 65;
            #pragma unroll
            for (int n1 = 0; n1 < 8; ++n1) g1[n1] = S[(8*k2 + n1)*65 + v_];
            fftN<8>(g1, twb);
        }
        if (t2 < 1040){
            int k2 = t2 / 65, v_ = t2 % 65;
            #pragma unroll
            for (int n1 = 0; n1 < 8; ++n1) g2[n1] = S[(8*k2 + n1)*65 + v_];
            fftN<8>(g2, twb);
        }
        __syncthreads();
        {
            int k2 = tid / 65, v_ = tid % 65;
            #pragma unroll
            for (int k1 = 0; k1 < 8; ++k1) S[(k2 + 16*k1)*65 + v_] = g0[k1];
        }
        {
            int k2 = t1 / 65, v_ = t1 % 65;
            #pragma unroll
            for (int k1 = 0; k1 < 8; ++k1) S[(k2 + 16*k1)*65 + v_] = g1[k1];
        }
        if (t2 < 1040){
            int k2 = t2 / 65, v_ = t2 % 65;
            #pragma unroll
            for (int k1 = 0; k1 < 8; ++k1) S[(k2 + 16*k1)*65 + v_] = g2[k1];
        }
    }
    __syncthreads();
    float2* dst = ((float2*)U_ws) + (size_t)img * 8320;
    for (int p = tid; p < 8320; p += 512) dst[p] = S[p];
}

// ---------------------------------------------------------------------------
// 3) sequential T-scan, U -> Y (separate buffers; compiler hoists U loads).
//    x' = 0.9a*x + (-KI*mu)*y + U ; y' = (KE*ga)*x + 0.9d*y.
// ---------------------------------------------------------------------------
__global__ __launch_bounds__(256) void k_scan(const float* __restrict__ U,
    float* __restrict__ Y,
    const float* __restrict__ KEw, const float* __restrict__ KIw,
    const float* __restrict__ gA, const float* __restrict__ gD,
    const float* __restrict__ gM, const float* __restrict__ gG)
{
    int g = blockIdx.x * 256 + threadIdx.x;
    if (g >= 4*3*128*65) return;
    int b = g / 24960, r = g % 24960;
    int c = r / 8320, uv = r % 8320;
    float2 ke = ((const float2*)KEw)[c*8320 + uv];
    float2 ki = ((const float2*)KIw)[c*8320 + uv];
    const float2* Up = (const float2*)U;
    float2* Yp = (float2*)Y;
    float xr = 0.f, xi = 0.f, yr = 0.f, yi = 0.f;
    #pragma unroll
    for (int t = 0; t < 32; ++t){
        int btc = (b*32 + t)*3 + c;
        float al = 0.9f * gA[btc], de = 0.9f * gD[btc];
        float mu = gM[btc],       ga = gG[btc];
        float axr = -ki.x * mu, axi = -ki.y * mu;
        float ayr =  ke.x * ga, ayi =  ke.y * ga;
        size_t iu = (size_t)btc * 8320 + uv;
        float2 uin = Up[iu];
        float nxr = fmaf(al, xr, fmaf(axr, yr, fmaf(-axi, yi, uin.x)));
        float nxi = fmaf(al, xi, fmaf(axr, yi, fmaf( axi, yr, uin.y)));
        float nyr = fmaf(ayr, xr, fmaf(-ayi, xi, de * yr));
        float nyi = fmaf(ayr, xi, fmaf( ayi, xr, de * yi));
        Yp[iu] = make_float2(nyr, nyi);
        xr = nxr; xi = nxi; yr = nyr; yi = nyi;
    }
}

// ---------------------------------------------------------------------------
// 4) inverse rfft2, single 65KB LDS buffer (2 blocks/CU).
//    col IFFT-128 (radix-16 in-place + radix-8 r/s/w), Hermitian EO-prep
//    paired-task in-place, row IFFT-64 (radix-8 in-place + radix-8 r/s/w).
// ---------------------------------------------------------------------------
__global__ __launch_bounds__(512, 4) void k_fft_inv(const float* __restrict__ Y_ws,
                                                    float* __restrict__ out)
{
    __shared__ c32 S[8320];                 // [128][65]
    __shared__ c32 Wt[128];                 // e^{+2 pi i t/128}
    const int tid = threadIdx.x;
    const int img = blockIdx.x;
    const int bt = img / 3, c = img % 3;

    if (tid < 128){
        float ang = 0.049087385212340517f * (float)tid;
        float s, co; sincosf(ang, &s, &co);
        Wt[tid] = make_float2(co, s);
    }
    __syncthreads();
    c32 twb[8];
    #pragma unroll
    for (int m = 0; m < 8; ++m) twb[m] = Wt[8*m];

    const float2* srcv = ((const float2*)Y_ws) + (size_t)img * 8320;
    for (int p = tid; p < 8320; p += 512) S[p] = srcv[p];
    __syncthreads();

    // col IFFT stage1: FFT16 over n2 at rows n1+8*n2 (task-owned). 520 tasks.
    for (int task = tid; task < 520; task += 512){
        int n1 = task / 65, v_ = task % 65;
        c32 v[16];
        #pragma unroll
        for (int n2 = 0; n2 < 16; ++n2) v[n2] = S[(n1 + 8*n2)*65 + v_];
        fftN<16>(v, twb);
        #pragma unroll
        for (int k2 = 0; k2 < 16; ++k2)
            S[(n1 + 8*k2)*65 + v_] = (n1 && k2) ? cmulc(Wt[n1*k2], v[k2]) : v[k2];
    }
    __syncthreads();
    // col IFFT stage2: FFT8 over n1 -> rows k2+16*k1. 1040 tasks, r/s/w.
    {
        c32 g0[8], g1[8], g2[8];
        const int t1 = tid + 512, t2 = tid + 1024;
        {
            int k2 = tid / 65, v_ = tid % 65;
            #pragma unroll
            for (int n1 = 0; n1 < 8; ++n1) g0[n1] = S[(8*k2 + n1)*65 + v_];
            fftN<8>(g0, twb);
        }
        {
            int k2 = t1 / 65, v_ = t1 % 65;
            #pragma unroll
            for (int n1 = 0; n1 < 8; ++n1) g1[n1] = S[(8*k2 + n1)*65 + v_];
            fftN<8>(g1, twb);
        }
        if (t2 < 1040){
            int k2 = t2 / 65, v_ = t2 % 65;
            #pragma unroll
            for (int n1 = 0; n1 < 8; ++n1) g2[n1] = S[(8*k2 + n1)*65 + v_];
            fftN<8>(g2, twb);
        }
        __syncthreads();
        {
            int k2 = tid / 65, v_ = tid % 65;
            #pragma unroll
            for (int k1 = 0; k1 < 8; ++k1) S[(k2 + 16*k1)*65 + v_] = g0[k1];
        }
        {
            int k2 = t1 / 65, v_ = t1 % 65;
            #pragma unroll
            for (int k1 = 0; k1 < 8; ++k1) S[(k2 + 16*k1)*65 + v_] = g1[k1];
        }
        if (t2 < 1040){
            int k2 = t2 / 65, v_ = t2 % 65;
            #pragma unroll
            for (int k1 = 0; k1 < 8; ++k1) S[(k2 + 16*k1)*65 + v_] = g2[k1];
        }
    }
    __syncthreads();
    // EO prep: paired tasks (k, 64-k) per row -> in-place. 128*33 tasks.
    // Z[k] = E[k] + i*O[k]; numpy drops imag of bins 0,64.
    for (int task = tid; task < 128*33; task += 512){
        int y = task / 33, k = task % 33;
        c32 Xk = S[y*65 + k];
        c32 Xn = S[y*65 + 64 - k];
        if (k == 0){ Xk.y = 0.f; Xn.y = 0.f; }
        float Er = 0.5f*(Xk.x + Xn.x), Ei = 0.5f*(Xk.y - Xn.y);
        c32 d  = make_float2(0.5f*(Xk.x - Xn.x), 0.5f*(Xk.y + Xn.y));
        c32 O  = cmulc(Wt[k], d);
        S[y*65 + k] = make_float2(Er - O.y, Ei + O.x);
        if (k > 0 && k < 32){
            float Er2 = 0.5f*(Xn.x + Xk.x), Ei2 = 0.5f*(Xn.y - Xk.y);
            c32 d2 = make_float2(0.5f*(Xn.x - Xk.x), 0.5f*(Xn.y + Xk.y));
            c32 O2 = cmulc(Wt[64 - k], d2);
            S[y*65 + 64 - k] = make_float2(Er2 - O2.y, Ei2 + O2.x);
        }
    }
    __syncthreads();
    // row IFFT-64 stage1: FFT8 over n2 at slots n1+8*n2 (task-owned),
    // twiddle W64^{n1*k2} = Wt[2*n1*k2]. 1024 tasks.
    for (int task = tid; task < 1024; task += 512){
        int y = task >> 3, n1 = task & 7;
        c32 v[8];
        #pragma unroll
        for (int n2 = 0; n2 < 8; ++n2) v[n2] = S[y*65 + n1 + 8*n2];
        fftN<8>(v, twb);
        #pragma unroll
        for (int k2 = 0; k2 < 8; ++k2)
            S[y*65 + n1 + 8*k2] = (n1 && k2) ? cmulc(Wt[2*n1*k2], v[k2]) : v[k2];
    }
    __syncthreads();
    // row IFFT-64 stage2: FFT8 over n1 (slots 8k2..8k2+7) -> slots k2+8*k1.
    // 1024 tasks, r/s/w.
    {
        c32 g0[8], g1[8];
        const int t1 = tid + 512;
        {
            int y = tid >> 3, k2 = tid & 7;
            #pragma unroll
            for (int n1 = 0; n1 < 8; ++n1) g0[n1] = S[y*65 + 8*k2 + n1];
            fftN<8>(g0, twb);
        }
        {
            int y = t1 >> 3, k2 = t1 & 7;
            #pragma unroll
            for (int n1 = 0; n1 < 8; ++n1) g1[n1] = S[y*65 + 8*k2 + n1];
            fftN<8>(g1, twb);
        }
        __syncthreads();
        {
            int y = tid >> 3, k2 = tid & 7;
            #pragma unroll
            for (int k1 = 0; k1 < 8; ++k1) S[y*65 + k2 + 8*k1] = g0[k1];
        }
        {
            int y = t1 >> 3, k2 = t1 & 7;
            #pragma unroll
            for (int k1 = 0; k1 < 8; ++k1) S[y*65 + k2 + 8*k1] = g1[k1];
        }
    }
    __syncthreads();
    // emit: x[2m] = Re z, x[2m+1] = Im z, scale 1/8192
    float* dst = out + (size_t)bt * 49152 + c;
    const float sc = 1.0f / 8192.0f;
    for (int p = tid; p < 8192; p += 512){
        int y = p >> 6, m = p & 63;
        c32 z = S[y*65 + m];
        dst[(size_t)((y << 7) + 2*m    ) * 3] = z.x * sc;
        dst[(size_t)((y << 7) + 2*m + 1) * 3] = z.y * sc;
    }
}

// ---------------------------------------------------------------------------
extern "C" void kernel_launch(void* const* d_in, const int* in_sizes, int n_in,
                              void* d_out, int out_size, void* d_ws, size_t ws_size,
                              hipStream_t stream)
{
    (void)in_sizes; (void)n_in; (void)out_size; (void)ws_size;
    const float* in   = (const float*)d_in[0];
    const float* cw   = (const float*)d_in[1];
    const float* cb   = (const float*)d_in[2];
    const float* wA   = (const float*)d_in[3];
    const float* bA   = (const float*)d_in[4];
    const float* wD   = (const float*)d_in[5];
    const float* bD   = (const float*)d_in[6];
    const float* wM   = (const float*)d_in[7];
    const float* bM   = (const float*)d_in[8];
    const float* wG   = (const float*)d_in[9];
    const float* bG   = (const float*)d_in[10];
    const float* kex  = (const float*)d_in[11];
    const float* kin  = (const float*)d_in[12];
    float* out = (float*)d_out;
    float* ws  = (float*)d_ws;

    float* part = ws;                    // 2048*32            = 65536
    float* gA   = ws + 65536;            // 384
    float* gD   = gA + 384;
    float* gM   = gD + 384;
    float* gG   = gM + 384;              // ends 67072
    float* KEw  = ws + 67072;            // 3*128*65*2         = 49920
    float* KIw  = KEw + 49920;           // ends 166912
    float* U    = ws + 166912;           // 128*3*128*65*2     = 6389760
    float* Yb   = U + 6389760;           // 6389760 (scan output, no alias)

    k_conv_spec<<<dim3(2048 + 195), dim3(256), 0, stream>>>(in, cw, cb, part,
                                                            kex, kin, KEw, KIw);
    k_fft_fwd  <<<dim3(512),        dim3(512), 0, stream>>>(in, U, part,
                                                            wA, bA, wD, bD, wM, bM, wG, bG,
                                                            gA, gD, gM, gG);
    k_scan     <<<dim3(390),        dim3(256), 0, stream>>>(U, Yb, KEw, KIw, gA, gD, gM, gG);
    k_fft_inv  <<<dim3(384),        dim3(512), 0, stream>>>(Yb, out);
}

// Round 13
// 93.454 us; speedup vs baseline: 2.8136x; 1.0110x over previous
//
#include <hip/hip_runtime.h>
#include <math.h>

typedef float2 c32;

__device__ __forceinline__ c32 cmulc(c32 a, c32 b){
    return make_float2(fmaf(a.x, b.x, -(a.y*b.y)), fmaf(a.x, b.y, a.y*b.x));
}
__device__ __forceinline__ c32 caddc(c32 a, c32 b){ return make_float2(a.x+b.x, a.y+b.y); }
__device__ __forceinline__ c32 csubc(c32 a, c32 b){ return make_float2(a.x-b.x, a.y-b.y); }

// In-register DIT FFT of size N (8 or 16), natural-order in/out.
// tw[m] = e^{sign*2*pi*i*m/16}  (sign baked into the table the caller built).
template<int N>
__device__ __forceinline__ void fftN(c32* a, const c32* tw){
    constexpr int LOG = (N == 16) ? 4 : 3;
    c32 b[N];
    #pragma unroll
    for (int i = 0; i < N; ++i){
        int r = 0;
        #pragma unroll
        for (int bb = 0; bb < LOG; ++bb) r = (r << 1) | ((i >> bb) & 1);
        b[i] = a[r];
    }
    #pragma unroll
    for (int len = 2; len <= N; len <<= 1){
        #pragma unroll
        for (int i = 0; i < N; i += len){
            #pragma unroll
            for (int j = 0; j < len/2; ++j){
                c32 t = b[i + j + len/2];
                if (j) t = cmulc(tw[j * (16/len)], t);
                c32 u = b[i + j];
                b[i + j]         = caddc(u, t);
                b[i + j + len/2] = csubc(u, t);
            }
        }
    }
    #pragma unroll
    for (int i = 0; i < N; ++i) a[i] = b[i];
}

// ---------------------------------------------------------------------------
// 1) merged: blocks 0..2047 = conv3x3 stride2 + gelu + stripe partial sums
//    (identical to R11 k_conv); blocks 2048.. = spectral rfft2 of padded
//    k_exc/k_inh (direct 256-tap DFT; backfills CUs as conv retires).
// ---------------------------------------------------------------------------
__global__ __launch_bounds__(256) void k_conv_spec(const float* __restrict__ in,
                                                   const float* __restrict__ cw,
                                                   const float* __restrict__ cb,
                                                   float* __restrict__ part,
                                                   const float* __restrict__ k_exc,
                                                   const float* __restrict__ k_inh,
                                                   float* __restrict__ KEw,
                                                   float* __restrict__ KIw)
{
    __shared__ float xs[9 * 392];          // conv: slab rows r0..r0+8
    __shared__ float red[64 * 33];         // conv: [wave*16+lane][ch]
    __shared__ float red2[8 * 33];         // conv: [rowgroup][ch]
    __shared__ c32 Wt[128];                // spectral: twiddles
    const int tid = threadIdx.x;

    if (blockIdx.x >= 2048){
        // ---- spectral branch ----
        if (tid < 128){
            float ang = -0.049087385212340517f * (float)tid;   // -2*pi*t/128
            float s, co; sincosf(ang, &s, &co);
            Wt[tid] = make_float2(co, s);
        }
        __syncthreads();
        int g = (blockIdx.x - 2048) * 256 + tid;
        if (g >= 2 * 24960) return;
        int which = g / 24960, r = g % 24960;
        int c = r / 8320, uv = r % 8320;
        int u_ = uv / 65, v_ = uv % 65;
        const float* kk = which ? k_inh : k_exc;
        float ar = 0.f, ai = 0.f;
        for (int y = 0; y < 16; ++y){
            int pu = u_ * (56 + y);
            #pragma unroll
            for (int x = 0; x < 16; ++x){
                int idx = (pu + v_ * (56 + x)) & 127;
                float kv = kk[(y*16 + x)*3 + c];
                c32 w = Wt[idx];
                ar = fmaf(kv, w.x, ar);
                ai = fmaf(kv, w.y, ai);
            }
        }
        ((float2*)(which ? KIw : KEw))[c*8320 + uv] = make_float2(ar, ai);
        return;
    }

    // ---- conv branch ----
    const int bt  = blockIdx.x >> 4;
    const int sr  = blockIdx.x & 15;
    const int r0  = 8 * sr;                // first input row of the stripe

    const float4* src4 = (const float4*)(in + (size_t)bt * 49152 + (size_t)r0 * 384);
    const float4 z4 = make_float4(0.f, 0.f, 0.f, 0.f);
    for (int i = tid; i < 9 * 98; i += 256){
        int r = i / 98, c4 = i - r * 98;
        float4 v = z4;
        if (c4 < 96 && (r0 + r) < 128) v = src4[r * 96 + c4];
        *(float4*)&xs[r * 392 + c4 * 4] = v;
    }
    __syncthreads();

    const int oyl = tid >> 6;              // local output row 0..3
    const int ox  = tid & 63;              // output col

    float f[27];
    #pragma unroll
    for (int ky = 0; ky < 3; ++ky){
        const int rb = (2 * oyl + ky) * 392 + 6 * ox;
        #pragma unroll
        for (int j = 0; j < 9; ++j) f[ky * 9 + j] = xs[rb + j];
    }

    float s[32];
    #pragma unroll
    for (int ch = 0; ch < 32; ++ch) s[ch] = cb[ch];
    #pragma unroll
    for (int q = 0; q < 27; ++q){
        const float fv = f[q];
        #pragma unroll
        for (int ch = 0; ch < 32; ++ch)
            s[ch] = fmaf(fv, cw[q*32 + ch], s[ch]);
    }

    #pragma unroll
    for (int ch = 0; ch < 32; ++ch){
        const float v  = s[ch];
        const float u_ = 0.7978845608028654f * fmaf(0.044715f * v, v * v, v);
        const float e_ = __builtin_amdgcn_exp2f(2.8853900817779268f * u_);
        const float t_ = 1.0f - 2.0f * __builtin_amdgcn_rcpf(1.0f + e_);
        s[ch] = 0.5f * v * (1.0f + t_);
    }

    #pragma unroll
    for (int ch = 0; ch < 32; ++ch){
        s[ch] += __shfl_down(s[ch], 32, 64);
        s[ch] += __shfl_down(s[ch], 16, 64);
    }
    const int wave = tid >> 6, lane = tid & 63;
    if (lane < 16){
        #pragma unroll
        for (int ch = 0; ch < 32; ++ch)
            red[(wave * 16 + lane) * 33 + ch] = s[ch];
    }
    __syncthreads();

    {
        const int grp = tid >> 5, ch = tid & 31;   // grp 0..7
        float acc = 0.0f;
        #pragma unroll
        for (int j = 0; j < 8; ++j)
            acc += red[(grp * 8 + j) * 33 + ch];
        red2[grp * 33 + ch] = acc;
    }
    __syncthreads();
    if (tid < 32){
        float acc = 0.0f;
        #pragma unroll
        for (int g2 = 0; g2 < 8; ++g2) acc += red2[g2 * 33 + tid];
        part[(size_t)blockIdx.x * 32 + tid] = acc;
    }
}

// ---------------------------------------------------------------------------
// 2) forward rfft2 (blocks 0..383, identical math to R11) + gates piggyback
//    (blocks 384..511: one bt each; tid<256 active; fits in the same
//    single block-wave since 384+128 = 512 = 256 CUs x 2 blocks/CU).
// ---------------------------------------------------------------------------
__global__ __launch_bounds__(512, 4) void k_fft_fwd(const float* __restrict__ in,
                                                    float* __restrict__ U_ws,
    const float* __restrict__ part,
    const float* __restrict__ wA, const float* __restrict__ bA,
    const float* __restrict__ wD, const float* __restrict__ bD,
    const float* __restrict__ wM, const float* __restrict__ bM,
    const float* __restrict__ wG, const float* __restrict__ bG,
    float* __restrict__ gA, float* __restrict__ gD,
    float* __restrict__ gM, float* __restrict__ gG)
{
    __shared__ c32 S[8320];                 // rows: [64][130]; cols: [128][65]
    __shared__ c32 Wt[128];                 // e^{-2 pi i t/128}
    const int tid = threadIdx.x;

    if (blockIdx.x >= 384){
        // ---- gates branch (parallel two-stage reduction) ----
        float* shred = (float*)S;            // 8*33 floats
        float* ctx   = ((float*)S) + 8 * 33; // 32 floats
        const int bt = blockIdx.x - 384;     // 0..127
        if (tid < 256){
            const int j = tid & 31, qg = tid >> 5;
            float acc = part[((size_t)(bt * 16 + 2 * qg    )) * 32 + j]
                      + part[((size_t)(bt * 16 + 2 * qg + 1)) * 32 + j];
            shred[qg * 33 + j] = acc;
        }
        __syncthreads();
        if (tid < 32){
            float s = 0.f;
            #pragma unroll
            for (int q = 0; q < 8; ++q) s += shred[q * 33 + tid];
            ctx[tid] = s * (1.0f / 4096.0f);
        }
        __syncthreads();
        if (tid < 12){
            const int gate = tid / 3, c = tid % 3;
            const float* w = (gate == 0) ? wA : (gate == 1) ? wD : (gate == 2) ? wM : wG;
            const float* b = (gate == 0) ? bA : (gate == 1) ? bD : (gate == 2) ? bM : bG;
            float s = b[c];
            #pragma unroll
            for (int jj = 0; jj < 32; ++jj) s = fmaf(ctx[jj], w[jj * 3 + c], s);
            const int o = bt * 3 + c;
            if (gate < 2){
                float v = 1.0f / (1.0f + expf(-s));
                ((gate == 0) ? gA : gD)[o] = v;
            } else {
                float v = fmaxf(s, 0.f) + log1pf(expf(-fabsf(s)));
                ((gate == 2) ? gM : gG)[o] = v;
            }
        }
        return;
    }

    // ---- forward FFT branch ----
    const int img = blockIdx.x;             // bt*3 + c
    const int bt = img / 3, c = img % 3;

    if (tid < 128){
        float ang = -0.049087385212340517f * (float)tid;
        float s, co; sincosf(ang, &s, &co);
        Wt[tid] = make_float2(co, s);
    }
    __syncthreads();
    c32 twb[8];
    #pragma unroll
    for (int m = 0; m < 8; ++m) twb[m] = Wt[8*m];   // 16th roots (serves FFT8 too)

    // pack: S[r*130+x] = in[2r][x] + i*in[2r+1][x]
    const float* src = in + (size_t)bt * 49152 + c;
    for (int p = tid; p < 8192; p += 512){
        int r = p >> 7, x = p & 127;
        float re = src[(size_t)((2*r)   * 128 + x) * 3];
        float im = src[(size_t)((2*r+1) * 128 + x) * 3];
        S[r*130 + x] = make_float2(re, im);
    }
    __syncthreads();

    // row stage1: FFT16 over n2 at slots n1+8*n2 (task-owned, in place),
    // then twiddle W128^{n1*k2}.  512 tasks = 512 threads.
    {
        int r = tid >> 3, n1 = tid & 7;
        c32 v[16];
        #pragma unroll
        for (int n2 = 0; n2 < 16; ++n2) v[n2] = S[r*130 + n1 + 8*n2];
        fftN<16>(v, twb);
        #pragma unroll
        for (int k2 = 0; k2 < 16; ++k2)
            S[r*130 + n1 + 8*k2] = (n1 && k2) ? cmulc(Wt[n1*k2], v[k2]) : v[k2];
    }
    __syncthreads();
    // row stage2: FFT8 over n1 (slots 8k2..8k2+7) -> slots k2+16*k1.
    // 1024 tasks, read-all/sync/write-all.
    {
        c32 g0[8], g1[8];
        const int t1 = tid + 512;
        {
            int r = tid >> 4, k2 = tid & 15;
            #pragma unroll
            for (int n1 = 0; n1 < 8; ++n1) g0[n1] = S[r*130 + 8*k2 + n1];
            fftN<8>(g0, twb);
        }
        {
            int r = t1 >> 4, k2 = t1 & 15;
            #pragma unroll
            for (int n1 = 0; n1 < 8; ++n1) g1[n1] = S[r*130 + 8*k2 + n1];
            fftN<8>(g1, twb);
        }
        __syncthreads();
        {
            int r = tid >> 4, k2 = tid & 15;
            #pragma unroll
            for (int k1 = 0; k1 < 8; ++k1) S[r*130 + k2 + 16*k1] = g0[k1];
        }
        {
            int r = t1 >> 4, k2 = t1 & 15;
            #pragma unroll
            for (int k1 = 0; k1 < 8; ++k1) S[r*130 + k2 + 16*k1] = g1[k1];
        }
    }
    __syncthreads();
    // unpack packed real rows -> C[128][65] layout, same buffer.
    // 4160 tasks; read-all/sync/write-all (<=9 tasks/thread).
    {
        c32 e0[9], e1[9];
        #pragma unroll
        for (int j = 0; j < 9; ++j){
            int task = tid + 512*j;
            if (task < 4160){
                int r = task / 65, v_ = task % 65;
                c32 zk = S[r*130 + v_];
                c32 zn = S[r*130 + ((128 - v_) & 127)];
                e0[j] = make_float2(0.5f*(zk.x + zn.x),  0.5f*(zk.y - zn.y));
                e1[j] = make_float2(0.5f*(zk.y + zn.y), -0.5f*(zk.x - zn.x));
            }
        }
        __syncthreads();
        #pragma unroll
        for (int j = 0; j < 9; ++j){
            int task = tid + 512*j;
            if (task < 4160){
                int r = task / 65, v_ = task % 65;
                S[(2*r)  *65 + v_] = e0[j];
                S[(2*r+1)*65 + v_] = e1[j];
            }
        }
    }
    __syncthreads();
    // col stage1: FFT16 over n2 at rows n1+8*n2 (task-owned), twiddle. 520 tasks.
    for (int task = tid; task < 520; task += 512){
        int n1 = task / 65, v_ = task % 65;
        c32 v[16];
        #pragma unroll
        for (int n2 = 0; n2 < 16; ++n2) v[n2] = S[(n1 + 8*n2)*65 + v_];
        fftN<16>(v, twb);
        #pragma unroll
        for (int k2 = 0; k2 < 16; ++k2)
            S[(n1 + 8*k2)*65 + v_] = (n1 && k2) ? cmulc(Wt[n1*k2], v[k2]) : v[k2];
    }
    __syncthreads();
    // col stage2: FFT8 over n1 (rows 8k2..8k2+7) -> rows k2+16*k1. 1040 tasks.
    {
        c32 g0[8], g1[8], g2[8];
        const int t1 = tid + 512, t2 = tid + 1024;
        {
            int k2 = tid / 65, v_ = tid % 65;
            #pragma unroll
            for (int n1 = 0; n1 < 8; ++n1) g0[n1] = S[(8*k2 + n1)*65 + v_];
            fftN<8>(g0, twb);
        }
        {
            int k2 = t1 / 65, v_ = t1 % 65;
            #pragma unroll
            for (int n1 = 0; n1 < 8; ++n1) g1[n1] = S[(8*k2 + n1)*65 + v_];
            fftN<8>(g1, twb);
        }
        if (t2 < 1040){
            int k2 = t2 / 65, v_ = t2 % 65;
            #pragma unroll
            for (int n1 = 0; n1 < 8; ++n1) g2[n1] = S[(8*k2 + n1)*65 + v_];
            fftN<8>(g2, twb);
        }
        __syncthreads();
        {
            int k2 = tid / 65, v_ = tid % 65;
            #pragma unroll
            for (int k1 = 0; k1 < 8; ++k1) S[(k2 + 16*k1)*65 + v_] = g0[k1];
        }
        {
            int k2 = t1 / 65, v_ = t1 % 65;
            #pragma unroll
            for (int k1 = 0; k1 < 8; ++k1) S[(k2 + 16*k1)*65 + v_] = g1[k1];
        }
        if (t2 < 1040){
            int k2 = t2 / 65, v_ = t2 % 65;
            #pragma unroll
            for (int k1 = 0; k1 < 8; ++k1) S[(k2 + 16*k1)*65 + v_] = g2[k1];
        }
    }
    __syncthreads();
    float2* dst = ((float2*)U_ws) + (size_t)img * 8320;
    for (int p = tid; p < 8320; p += 512) dst[p] = S[p];
}

// ---------------------------------------------------------------------------
// 3) sequential T-scan, U -> Y (separate buffers; compiler hoists U loads).
//    x' = 0.9a*x + (-KI*mu)*y + U ; y' = (KE*ga)*x + 0.9d*y.
// ---------------------------------------------------------------------------
__global__ __launch_bounds__(256) void k_scan(const float* __restrict__ U,
    float* __restrict__ Y,
    const float* __restrict__ KEw, const float* __restrict__ KIw,
    const float* __restrict__ gA, const float* __restrict__ gD,
    const float* __restrict__ gM, const float* __restrict__ gG)
{
    int g = blockIdx.x * 256 + threadIdx.x;
    if (g >= 4*3*128*65) return;
    int b = g / 24960, r = g % 24960;
    int c = r / 8320, uv = r % 8320;
    float2 ke = ((const float2*)KEw)[c*8320 + uv];
    float2 ki = ((const float2*)KIw)[c*8320 + uv];
    const float2* Up = (const float2*)U;
    float2* Yp = (float2*)Y;
    float xr = 0.f, xi = 0.f, yr = 0.f, yi = 0.f;
    #pragma unroll
    for (int t = 0; t < 32; ++t){
        int btc = (b*32 + t)*3 + c;
        float al = 0.9f * gA[btc], de = 0.9f * gD[btc];
        float mu = gM[btc],       ga = gG[btc];
        float axr = -ki.x * mu, axi = -ki.y * mu;
        float ayr =  ke.x * ga, ayi =  ke.y * ga;
        size_t iu = (size_t)btc * 8320 + uv;
        float2 uin = Up[iu];
        float nxr = fmaf(al, xr, fmaf(axr, yr, fmaf(-axi, yi, uin.x)));
        float nxi = fmaf(al, xi, fmaf(axr, yi, fmaf( axi, yr, uin.y)));
        float nyr = fmaf(ayr, xr, fmaf(-ayi, xi, de * yr));
        float nyi = fmaf(ayr, xi, fmaf( ayi, xr, de * yi));
        Yp[iu] = make_float2(nyr, nyi);
        xr = nxr; xi = nxi; yr = nyr; yi = nyi;
    }
}

// ---------------------------------------------------------------------------
// 4) inverse rfft2, single 65KB LDS buffer (2 blocks/CU).
//    col IFFT-128 (radix-16 in-place + radix-8 r/s/w), Hermitian EO-prep
//    paired-task in-place, row IFFT-64 (radix-8 in-place + radix-8 r/s/w).
// ---------------------------------------------------------------------------
__global__ __launch_bounds__(512, 4) void k_fft_inv(const float* __restrict__ Y_ws,
                                                    float* __restrict__ out)
{
    __shared__ c32 S[8320];                 // [128][65]
    __shared__ c32 Wt[128];                 // e^{+2 pi i t/128}
    const int tid = threadIdx.x;
    const int img = blockIdx.x;
    const int bt = img / 3, c = img % 3;

    if (tid < 128){
        float ang = 0.049087385212340517f * (float)tid;
        float s, co; sincosf(ang, &s, &co);
        Wt[tid] = make_float2(co, s);
    }
    __syncthreads();
    c32 twb[8];
    #pragma unroll
    for (int m = 0; m < 8; ++m) twb[m] = Wt[8*m];

    const float2* srcv = ((const float2*)Y_ws) + (size_t)img * 8320;
    for (int p = tid; p < 8320; p += 512) S[p] = srcv[p];
    __syncthreads();

    // col IFFT stage1: FFT16 over n2 at rows n1+8*n2 (task-owned). 520 tasks.
    for (int task = tid; task < 520; task += 512){
        int n1 = task / 65, v_ = task % 65;
        c32 v[16];
        #pragma unroll
        for (int n2 = 0; n2 < 16; ++n2) v[n2] = S[(n1 + 8*n2)*65 + v_];
        fftN<16>(v, twb);
        #pragma unroll
        for (int k2 = 0; k2 < 16; ++k2)
            S[(n1 + 8*k2)*65 + v_] = (n1 && k2) ? cmulc(Wt[n1*k2], v[k2]) : v[k2];
    }
    __syncthreads();
    // col IFFT stage2: FFT8 over n1 -> rows k2+16*k1. 1040 tasks, r/s/w.
    {
        c32 g0[8], g1[8], g2[8];
        const int t1 = tid + 512, t2 = tid + 1024;
        {
            int k2 = tid / 65, v_ = tid % 65;
            #pragma unroll
            for (int n1 = 0; n1 < 8; ++n1) g0[n1] = S[(8*k2 + n1)*65 + v_];
            fftN<8>(g0, twb);
        }
        {
            int k2 = t1 / 65, v_ = t1 % 65;
            #pragma unroll
            for (int n1 = 0; n1 < 8; ++n1) g1[n1] = S[(8*k2 + n1)*65 + v_];
            fftN<8>(g1, twb);
        }
        if (t2 < 1040){
            int k2 = t2 / 65, v_ = t2 % 65;
            #pragma unroll
            for (int n1 = 0; n1 < 8; ++n1) g2[n1] = S[(8*k2 + n1)*65 + v_];
            fftN<8>(g2, twb);
        }
        __syncthreads();
        {
            int k2 = tid / 65, v_ = tid % 65;
            #pragma unroll
            for (int k1 = 0; k1 < 8; ++k1) S[(k2 + 16*k1)*65 + v_] = g0[k1];
        }
        {
            int k2 = t1 / 65, v_ = t1 % 65;
            #pragma unroll
            for (int k1 = 0; k1 < 8; ++k1) S[(k2 + 16*k1)*65 + v_] = g1[k1];
        }
        if (t2 < 1040){
            int k2 = t2 / 65, v_ = t2 % 65;
            #pragma unroll
            for (int k1 = 0; k1 < 8; ++k1) S[(k2 + 16*k1)*65 + v_] = g2[k1];
        }
    }
    __syncthreads();
    // EO prep: paired tasks (k, 64-k) per row -> in-place. 128*33 tasks.
    // Z[k] = E[k] + i*O[k]; numpy drops imag of bins 0,64.
    for (int task = tid; task < 128*33; task += 512){
        int y = task / 33, k = task % 33;
        c32 Xk = S[y*65 + k];
        c32 Xn = S[y*65 + 64 - k];
        if (k == 0){ Xk.y = 0.f; Xn.y = 0.f; }
        float Er = 0.5f*(Xk.x + Xn.x), Ei = 0.5f*(Xk.y - Xn.y);
        c32 d  = make_float2(0.5f*(Xk.x - Xn.x), 0.5f*(Xk.y + Xn.y));
        c32 O  = cmulc(Wt[k], d);
        S[y*65 + k] = make_float2(Er - O.y, Ei + O.x);
        if (k > 0 && k < 32){
            float Er2 = 0.5f*(Xn.x + Xk.x), Ei2 = 0.5f*(Xn.y - Xk.y);
            c32 d2 = make_float2(0.5f*(Xn.x - Xk.x), 0.5f*(Xn.y + Xk.y));
            c32 O2 = cmulc(Wt[64 - k], d2);
            S[y*65 + 64 - k] = make_float2(Er2 - O2.y, Ei2 + O2.x);
        }
    }
    __syncthreads();
    // row IFFT-64 stage1: FFT8 over n2 at slots n1+8*n2 (task-owned),
    // twiddle W64^{n1*k2} = Wt[2*n1*k2]. 1024 tasks.
    for (int task = tid; task < 1024; task += 512){
        int y = task >> 3, n1 = task & 7;
        c32 v[8];
        #pragma unroll
        for (int n2 = 0; n2 < 8; ++n2) v[n2] = S[y*65 + n1 + 8*n2];
        fftN<8>(v, twb);
        #pragma unroll
        for (int k2 = 0; k2 < 8; ++k2)
            S[y*65 + n1 + 8*k2] = (n1 && k2) ? cmulc(Wt[2*n1*k2], v[k2]) : v[k2];
    }
    __syncthreads();
    // row IFFT-64 stage2: FFT8 over n1 (slots 8k2..8k2+7) -> slots k2+8*k1.
    // 1024 tasks, r/s/w.
    {
        c32 g0[8], g1[8];
        const int t1 = tid + 512;
        {
            int y = tid >> 3, k2 = tid & 7;
            #pragma unroll
            for (int n1 = 0; n1 < 8; ++n1) g0[n1] = S[y*65 + 8*k2 + n1];
            fftN<8>(g0, twb);
        }
        {
            int y = t1 >> 3, k2 = t1 & 7;
            #pragma unroll
            for (int n1 = 0; n1 < 8; ++n1) g1[n1] = S[y*65 + 8*k2 + n1];
            fftN<8>(g1, twb);
        }
        __syncthreads();
        {
            int y = tid >> 3, k2 = tid & 7;
            #pragma unroll
            for (int k1 = 0; k1 < 8; ++k1) S[y*65 + k2 + 8*k1] = g0[k1];
        }
        {
            int y = t1 >> 3, k2 = t1 & 7;
            #pragma unroll
            for (int k1 = 0; k1 < 8; ++k1) S[y*65 + k2 + 8*k1] = g1[k1];
        }
    }
    __syncthreads();
    // emit: x[2m] = Re z, x[2m+1] = Im z, scale 1/8192
    float* dst = out + (size_t)bt * 49152 + c;
    const float sc = 1.0f / 8192.0f;
    for (int p = tid; p < 8192; p += 512){
        int y = p >> 6, m = p & 63;
        c32 z = S[y*65 + m];
        dst[(size_t)((y << 7) + 2*m    ) * 3] = z.x * sc;
        dst[(size_t)((y << 7) + 2*m + 1) * 3] = z.y * sc;
    }
}

// ---------------------------------------------------------------------------
extern "C" void kernel_launch(void* const* d_in, const int* in_sizes, int n_in,
                              void* d_out, int out_size, void* d_ws, size_t ws_size,
                              hipStream_t stream)
{
    (void)in_sizes; (void)n_in; (void)out_size; (void)ws_size;
    const float* in   = (const float*)d_in[0];
    const float* cw   = (const float*)d_in[1];
    const float* cb   = (const float*)d_in[2];
    const float* wA   = (const float*)d_in[3];
    const float* bA   = (const float*)d_in[4];
    const float* wD   = (const float*)d_in[5];
    const float* bD   = (const float*)d_in[6];
    const float* wM   = (const float*)d_in[7];
    const float* bM   = (const float*)d_in[8];
    const float* wG   = (const float*)d_in[9];
    const float* bG   = (const float*)d_in[10];
    const float* kex  = (const float*)d_in[11];
    const float* kin  = (const float*)d_in[12];
    float* out = (float*)d_out;
    float* ws  = (float*)d_ws;

    float* part = ws;                    // 2048*32            = 65536
    float* gA   = ws + 65536;            // 384
    float* gD   = gA + 384;
    float* gM   = gD + 384;
    float* gG   = gM + 384;              // ends 67072
    float* KEw  = ws + 67072;            // 3*128*65*2         = 49920
    float* KIw  = KEw + 49920;           // ends 166912
    float* U    = ws + 166912;           // 128*3*128*65*2     = 6389760
    float* Yb   = U + 6389760;           // 6389760 (scan output, no alias)

    k_conv_spec<<<dim3(2048 + 195), dim3(256), 0, stream>>>(in, cw, cb, part,
                                                            kex, kin, KEw, KIw);
    k_fft_fwd  <<<dim3(512),        dim3(512), 0, stream>>>(in, U, part,
                                                            wA, bA, wD, bD, wM, bM, wG, bG,
                                                            gA, gD, gM, gG);
    k_scan     <<<dim3(390),        dim3(256), 0, stream>>>(U, Yb, KEw, KIw, gA, gD, gM, gG);
    k_fft_inv  <<<dim3(384),        dim3(512), 0, stream>>>(Yb, out);
}